// Round 8
// baseline (304.081 us; speedup 1.0000x reference)
//
#include <hip/hip_runtime.h>
#include <cstdint>
#include <cstddef>

#define B_  8
#define N_  512
#define E_  512
#define H_  8
#define DH_ 64
#define NE_ 16384
#define QT  64

using u16   = unsigned short;
using bf16x8 = __attribute__((ext_vector_type(8))) __bf16;
using u16x8  = __attribute__((ext_vector_type(8))) unsigned short;
using f32x4  = __attribute__((ext_vector_type(4))) float;

// fp32 -> bf16 round-to-nearest-even
__device__ __forceinline__ u16 f2b(float f) {
  unsigned u = __builtin_bit_cast(unsigned, f);
  u += 0x7fffu + ((u >> 16) & 1u);
  return (u16)(u >> 16);
}

__device__ __forceinline__ bf16x8 ld_frag(const u16* p) {
  return __builtin_bit_cast(bf16x8, *(const u16x8*)p);
}

// Async global->LDS, 16B per lane. LDS dest is wave-uniform base + lane*16.
__device__ __forceinline__ void gld_lds16(const u16* g, u16* l) {
  __builtin_amdgcn_global_load_lds(
      (const __attribute__((address_space(1))) unsigned*)(g),
      (__attribute__((address_space(3))) unsigned*)(l), 16, 0, 0);
}

// ---------------------------------------------------------------------------
// Core 128x128 block-tile GEMM, C = A[128xK] * W[128xK]^T, bf16 in, fp32 acc.
// ---------------------------------------------------------------------------
__device__ __forceinline__ void gemm_core_128x128(
    const u16* __restrict__ At, int lda,
    const u16* __restrict__ Bt, int ldb, int K,
    u16* ldsA, u16* ldsB, f32x4 (&acc)[4][4]) {
  const int tid  = threadIdx.x;
  const int wid  = tid >> 6, lane = tid & 63;
  const int wr   = wid >> 1, wc = wid & 1;
  const int qd   = lane >> 4, r = lane & 15;
  const int mrow = tid >> 2, k0 = (tid & 3) * 8;
  const int wbase = wid << 9;          // u16 units: 64 lanes * 8 u16
  for (int kt = 0; kt < K; kt += 32) {
    __syncthreads();
    gld_lds16(&At[(size_t)mrow*lda + kt + k0],        ldsA + wbase);
    gld_lds16(&At[(size_t)(mrow+64)*lda + kt + k0],   ldsA + 64*32 + wbase);
    gld_lds16(&Bt[(size_t)mrow*ldb + kt + k0],        ldsB + wbase);
    gld_lds16(&Bt[(size_t)(mrow+64)*ldb + kt + k0],   ldsB + 64*32 + wbase);
    __syncthreads();
    bf16x8 af[4], bfv[4];
#pragma unroll
    for (int i = 0; i < 4; ++i) af[i] = ld_frag(&ldsA[(wr*64 + i*16 + r)*32 + qd*8]);
#pragma unroll
    for (int j = 0; j < 4; ++j) bfv[j] = ld_frag(&ldsB[(wc*64 + j*16 + r)*32 + qd*8]);
#pragma unroll
    for (int i = 0; i < 4; ++i)
#pragma unroll
      for (int j = 0; j < 4; ++j)
        acc[i][j] = __builtin_amdgcn_mfma_f32_16x16x32_bf16(af[i], bfv[j], acc[i][j], 0, 0, 0);
  }
}

// EPI 0: bf16 out = acc + bias
// EPI 1: f32  out = acc + bias + res
// EPI 2: bf16 out = gelu_exact(acc + bias)
template <int EPI>
__global__ __launch_bounds__(256) void gemm_epi(
    const u16* __restrict__ A, const u16* __restrict__ W,
    const float* __restrict__ bias, const float* __restrict__ res,
    float* __restrict__ outf, u16* __restrict__ outb, int Kd, int Nd) {
  __shared__ u16 ldsA[128*32];
  __shared__ u16 ldsB[128*32];
  const int bx = blockIdx.x, by = blockIdx.y;
  f32x4 acc[4][4] = {};
  gemm_core_128x128(A + (size_t)bx*128*Kd, Kd, W + (size_t)by*128*Kd, Kd, Kd,
                    ldsA, ldsB, acc);
  const int tid = threadIdx.x, wid = tid>>6, lane = tid&63;
  const int wr = wid>>1, wc = wid&1, qd = lane>>4, r = lane&15;
#pragma unroll
  for (int i = 0; i < 4; ++i) {
#pragma unroll
    for (int j = 0; j < 4; ++j) {
      const int grow = bx*128 + wr*64 + i*16 + qd*4;
      const int gcol = by*128 + wc*64 + j*16 + r;
      const float bb = bias[gcol];
#pragma unroll
      for (int rg = 0; rg < 4; ++rg) {
        float v = acc[i][j][rg] + bb;
        const size_t idx = (size_t)(grow + rg)*Nd + gcol;
        if constexpr (EPI == 0) {
          outb[idx] = f2b(v);
        } else if constexpr (EPI == 1) {
          outf[idx] = v + res[idx];
        } else {
          v = 0.5f * v * (1.0f + erff(v * 0.70710678118f));
          outb[idx] = f2b(v);
        }
      }
    }
  }
}

// Split-K GEMM: grid.z = K-slice; raw fp32 partials to part[s][M][Nd].
__global__ __launch_bounds__(256) void gemm_splitk_k(
    const u16* __restrict__ A, const u16* __restrict__ W,
    float* __restrict__ part, int Kd, int Nd, int Ks) {
  __shared__ u16 ldsA[128*32];
  __shared__ u16 ldsB[128*32];
  const int bx = blockIdx.x, by = blockIdx.y, s = blockIdx.z;
  f32x4 acc[4][4] = {};
  gemm_core_128x128(A + (size_t)bx*128*Kd + (size_t)s*Ks, Kd,
                    W + (size_t)by*128*Kd + (size_t)s*Ks, Kd, Ks,
                    ldsA, ldsB, acc);
  const int tid = threadIdx.x, wid = tid>>6, lane = tid&63;
  const int wr = wid>>1, wc = wid&1, qd = lane>>4, r = lane&15;
  float* po = part + (size_t)s*(B_*N_)*Nd;
#pragma unroll
  for (int i = 0; i < 4; ++i) {
#pragma unroll
    for (int j = 0; j < 4; ++j) {
      const int grow = bx*128 + wr*64 + i*16 + qd*4;
      const int gcol = by*128 + wc*64 + j*16 + r;
#pragma unroll
      for (int rg = 0; rg < 4; ++rg)
        po[(size_t)(grow + rg)*Nd + gcol] = acc[i][j][rg];
    }
  }
}

// out = sum_s part[s] + bias + res   (fp32, float4-vectorized; Nd == E_)
template <int S>
__global__ __launch_bounds__(256) void splitk_reduce_k(
    const float* __restrict__ part, const float* __restrict__ bias,
    const float* __restrict__ res, float* __restrict__ out) {
  const size_t base = ((size_t)blockIdx.x*256 + threadIdx.x) * 4;
  float4 v = *(const float4*)&res[base];
  const int col = (int)(base & (E_-1));
  const float4 bb = *(const float4*)&bias[col];
  v.x += bb.x; v.y += bb.y; v.z += bb.z; v.w += bb.w;
#pragma unroll
  for (int s = 0; s < S; ++s) {
    const float4 p = *(const float4*)&part[(size_t)s*(B_*N_*E_) + base];
    v.x += p.x; v.y += p.y; v.z += p.z; v.w += p.w;
  }
  *(float4*)&out[base] = v;
}

// LayerNorm helper: block of 256 threads, one row of 512.
__device__ __forceinline__ void ln_store(
    float v0, float v1, const float* __restrict__ g,
    const float* __restrict__ be, u16* __restrict__ outb, int row, int t) {
  float s = v0 + v1, ss = v0*v0 + v1*v1;
  for (int o = 32; o; o >>= 1) { s += __shfl_down(s, o); ss += __shfl_down(ss, o); }
  __shared__ float rs[4], rss[4];
  const int wid = t>>6, lane = t&63;
  if (!lane) { rs[wid] = s; rss[wid] = ss; }
  __syncthreads();
  s  = rs[0]+rs[1]+rs[2]+rs[3];
  ss = rss[0]+rss[1]+rss[2]+rss[3];
  const float mu   = s * (1.0f/E_);
  const float var  = ss * (1.0f/E_) - mu*mu;
  const float rstd = rsqrtf(var + 1e-5f);
  outb[(size_t)row*E_ + t]       = f2b((v0-mu)*rstd*g[t] + be[t]);
  outb[(size_t)row*E_ + t + 256] = f2b((v1-mu)*rstd*g[t+256] + be[t+256]);
}

// Wo split-K reduce (S=2) fused with +bias +residual -> x1 AND LN2 -> h2 bf16.
__global__ __launch_bounds__(256) void splitk_reduce_ln_k(
    const float* __restrict__ part, const float* __restrict__ bias,
    const float* __restrict__ res, float* __restrict__ x1,
    const float* __restrict__ g, const float* __restrict__ be,
    u16* __restrict__ h2b) {
  const int row = blockIdx.x, t = threadIdx.x;
  const size_t base = (size_t)row*E_;
  float v0 = res[base + t]       + bias[t];
  float v1 = res[base + t + 256] + bias[t + 256];
#pragma unroll
  for (int s = 0; s < 2; ++s) {
    v0 += part[(size_t)s*(B_*N_*E_) + base + t];
    v1 += part[(size_t)s*(B_*N_*E_) + base + t + 256];
  }
  x1[base + t] = v0; x1[base + t + 256] = v1;
  ln_store(v0, v1, g, be, h2b, row, t);
}

// Merged QKV projection + edge encoder/scatter.
// z in 0..2: QKV GEMM slice z. z==3: 128 blocks of edge-encoder work
// (HBM-bound; overlaps the compute-bound GEMM slices).
__global__ __launch_bounds__(256) void qkv_edge_k(
    const u16* __restrict__ A,
    const u16* __restrict__ Wqb, const u16* __restrict__ Wkb, const u16* __restrict__ Wvb,
    const float* __restrict__ bq, const float* __restrict__ bk, const float* __restrict__ bv,
    u16* __restrict__ qo, u16* __restrict__ ko, u16* __restrict__ vo,
    const float* __restrict__ ea, const float* __restrict__ We,
    const float* __restrict__ be, const int* __restrict__ ei,
    float* __restrict__ eb) {
  __shared__ u16 ldsA[128*32];
  __shared__ u16 ldsB[128*32];
  const int bx = blockIdx.x, by = blockIdx.y, z = blockIdx.z;
  if (z == 3) {
    // ---- edge encoder + scatter: 128 blocks = 512 waves, 32 edges/wave ----
    const int wglob = ((by*32 + bx)*256 + (int)threadIdx.x) >> 6;
    const int lane  = threadIdx.x & 63;
    float w[8][8];
#pragma unroll
    for (int h = 0; h < 8; ++h) {
      const float4 f0 = *(const float4*)&We[h*E_ + lane*8];
      const float4 f1 = *(const float4*)&We[h*E_ + lane*8 + 4];
      w[h][0]=f0.x; w[h][1]=f0.y; w[h][2]=f0.z; w[h][3]=f0.w;
      w[h][4]=f1.x; w[h][5]=f1.y; w[h][6]=f1.z; w[h][7]=f1.w;
    }
    const float beh = (lane < 8) ? be[lane] : 0.f;
#pragma unroll 1
    for (int t = 0; t < NE_/512; ++t) {          // 32 edges per wave
      const int e = wglob*(NE_/512) + t;
      const float* ar = ea + (size_t)e*E_;
      const float4 a0 = *(const float4*)&ar[lane*8];
      const float4 a1 = *(const float4*)&ar[lane*8 + 4];
      const float a[8] = {a0.x,a0.y,a0.z,a0.w,a1.x,a1.y,a1.z,a1.w};
      float acc[8];
#pragma unroll
      for (int h = 0; h < 8; ++h) {
        float s = 0.f;
#pragma unroll
        for (int j = 0; j < 8; ++j) s += a[j]*w[h][j];
        acc[h] = s;
      }
#pragma unroll
      for (int h = 0; h < 8; ++h) {
        float v = acc[h];
        v += __shfl_xor(v, 1);  v += __shfl_xor(v, 2);  v += __shfl_xor(v, 4);
        v += __shfl_xor(v, 8);  v += __shfl_xor(v, 16); v += __shfl_xor(v, 32);
        acc[h] = v;
      }
      float myv = acc[0];
#pragma unroll
      for (int h = 1; h < 8; ++h) myv = (lane == h) ? acc[h] : myv;
      if (lane < 8) {
        const int s2 = ei[e], t2 = ei[NE_ + e];
        atomicAdd(&eb[((size_t)lane*N_ + s2)*N_ + t2], myv + beh);
      }
    }
    return;
  }
  const u16*   W    = z == 0 ? Wqb : (z == 1 ? Wkb : Wvb);
  const float* bias = z == 0 ? bq  : (z == 1 ? bk  : bv);
  u16*         outb = z == 0 ? qo  : (z == 1 ? ko  : vo);
  f32x4 acc[4][4] = {};
  gemm_core_128x128(A + (size_t)bx*128*E_, E_, W + (size_t)by*128*E_, E_, E_,
                    ldsA, ldsB, acc);
  const int tid = threadIdx.x, wid = tid>>6, lane = tid&63;
  const int wr = wid>>1, wc = wid&1, qd = lane>>4, r = lane&15;
#pragma unroll
  for (int i = 0; i < 4; ++i) {
#pragma unroll
    for (int j = 0; j < 4; ++j) {
      const int grow = bx*128 + wr*64 + i*16 + qd*4;
      const int gcol = by*128 + wc*64 + j*16 + r;
      const float bb = bias[gcol];
#pragma unroll
      for (int rg = 0; rg < 4; ++rg)
        outb[(size_t)(grow + rg)*E_ + gcol] = f2b(acc[i][j][rg] + bb);
    }
  }
}

// ---------------------------------------------------------------------------
// Flash attention v3: wave-private q-rows. Each wave owns 16 q-rows x all
// 128 m-cols, so softmax row max/sum are pure 16-lane shfl reductions —
// NO cross-wave LDS exchange, NO sM/sL/sAlpha, 2 barriers/iter (staging only).
// P goes through a per-wave sP region (same-wave write->read, lgkmcnt only).
// Q loads are direct global->VGPR (A-layout addressable). No dynamic register
// indexing anywhere (R5/R6 scratch-spill lesson). sVt keeps the XOR column
// swizzle (conflict-free write, 16B-contiguous read).
// ---------------------------------------------------------------------------
__global__ __launch_bounds__(256) void flash_attn_k(
    const u16* __restrict__ qm, const u16* __restrict__ km, const u16* __restrict__ vm,
    const float* __restrict__ dtab, const int* __restrict__ Dm,
    const float* __restrict__ ebias, u16* __restrict__ outb) {
  __shared__ u16 sK[2*128*32];      // [ks][row][32]   16 KB
  __shared__ u16 sVt[64*136];       // [d][m^swz]      17 KB
  __shared__ u16 sP[4*16*136];      // per-wave [16][136]  17 KB
  __shared__ float sDt[104];

  const int bx = blockIdx.x;
  const int bz = blockIdx.y; const int b = bz>>3, h = bz&7;
  const int n0 = bx*QT;
  const int tid = threadIdx.x, wid = tid>>6, lane = tid&63;
  const int qd = lane>>4, r = lane&15;
  const int lrow = lane>>2, lk = (lane&3)*8;

  const u16* Qg = qm + ((size_t)(b*N_ + n0 + wid*16))*E_ + h*DH_;
  const u16* Kg = km + (size_t)b*N_*E_ + h*DH_;
  const u16* Vg = vm + (size_t)b*N_*E_ + h*DH_;
  const int*   Db = Dm + (size_t)b*N_*N_;
  const float* Eb = ebias + (size_t)h*N_*N_;
  u16* sPw = sP + wid*16*136;

  // Q fragments direct to registers: A-layout row=lane&15, k=qd*8+j (+32ks)
  bf16x8 qf[2];
#pragma unroll
  for (int ks = 0; ks < 2; ++ks)
    qf[ks] = ld_frag(&Qg[(size_t)r*E_ + ks*32 + qd*8]);
  for (int idx = tid; idx < 100; idx += 256) sDt[idx] = dtab[idx*H_ + h];

  float mI[4], lI[4];
#pragma unroll
  for (int rg = 0; rg < 4; ++rg) { mI[rg] = -3.0e38f; lI[rg] = 0.f; }
  f32x4 accO[4] = {};   // 4 d-tiles; C layout row=qd*4+rg, col=t*16+r

  for (int mc = 0; mc < N_; mc += 128) {
    __syncthreads();   // (1) protect sK/sVt from prev-iter readers
#pragma unroll
    for (int t = 0; t < 2; ++t) {
      const int row0 = wid*32 + t*16;
#pragma unroll
      for (int ks = 0; ks < 2; ++ks)
        gld_lds16(&Kg[(size_t)(mc + row0 + lrow)*E_ + ks*32 + lk],
                  sK + ks*4096 + row0*32);
    }
#pragma unroll
    for (int it = 0; it < 4; ++it) {
      const int idx = it*256 + tid;
      const int m = idx>>3, d0 = (idx&7)*8;
      const int g = d0>>3;
      const u16x8 u = *(const u16x8*)&Vg[(size_t)(mc+m)*E_ + d0];
#pragma unroll
      for (int e = 0; e < 8; ++e)
        sVt[(d0+e)*136 + (m ^ (g<<3))] = u[e];   // static reg index
    }
    __syncthreads();   // (2) publish staged K/V
    // ---- S = Q K^T : 8 m-tiles per wave ----
    f32x4 accS[8] = {};
#pragma unroll
    for (int ks = 0; ks < 2; ++ks)
#pragma unroll
      for (int j = 0; j < 8; ++j) {
        const bf16x8 bfv = ld_frag(&sK[ks*4096 + (j*16 + r)*32 + qd*8]);
        accS[j] = __builtin_amdgcn_mfma_f32_16x16x32_bf16(qf[ks], bfv, accS[j], 0, 0, 0);
      }
    // ---- bias + row max (wave-local) ----
    float nmax[4];
#pragma unroll
    for (int rg = 0; rg < 4; ++rg) nmax[rg] = -3.0e38f;
    const int nbase = n0 + wid*16 + qd*4;
#pragma unroll
    for (int j = 0; j < 8; ++j) {
      const int m = mc + j*16 + r;
#pragma unroll
      for (int rg = 0; rg < 4; ++rg) {
        int di = Db[(size_t)(nbase+rg)*N_ + m];
        di = di < 0 ? 0 : (di > 99 ? 99 : di);
        const float v = accS[j][rg]*0.125f + sDt[di] + Eb[(size_t)(nbase+rg)*N_ + m];
        accS[j][rg] = v;
        nmax[rg] = fmaxf(nmax[rg], v);
      }
    }
    float alph[4];
#pragma unroll
    for (int rg = 0; rg < 4; ++rg) {
      float v = nmax[rg];
      v = fmaxf(v, __shfl_xor(v, 1)); v = fmaxf(v, __shfl_xor(v, 2));
      v = fmaxf(v, __shfl_xor(v, 4)); v = fmaxf(v, __shfl_xor(v, 8));
      const float mnew = fmaxf(mI[rg], v);
      alph[rg] = __expf(mI[rg] - mnew);
      mI[rg] = mnew;
    }
    // ---- P = exp(S-m) -> per-wave sP; row sums; O rescale ----
#pragma unroll
    for (int rg = 0; rg < 4; ++rg) {
      const float mrow = mI[rg];
      float partial = 0.f;
#pragma unroll
      for (int j = 0; j < 8; ++j) {
        const float p = __expf(accS[j][rg] - mrow);
        partial += p;
        sPw[(qd*4+rg)*136 + j*16 + r] = f2b(p);
      }
      float v = partial;
      v += __shfl_xor(v, 1); v += __shfl_xor(v, 2);
      v += __shfl_xor(v, 4); v += __shfl_xor(v, 8);
      lI[rg] = lI[rg]*alph[rg] + v;
#pragma unroll
      for (int t = 0; t < 4; ++t) accO[t][rg] *= alph[rg];
    }
    // ---- O += P @ V  (same-wave sP read; compiler inserts lgkmcnt wait) ----
#pragma unroll
    for (int ks2 = 0; ks2 < 4; ++ks2) {
      const bf16x8 af = ld_frag(&sPw[r*136 + ks2*32 + qd*8]);
#pragma unroll
      for (int t = 0; t < 4; ++t) {
        const int d = t*16 + r;
        const int mb = (ks2*32 + qd*8) ^ (((d>>3)&7)<<3);
        const bf16x8 bfv = ld_frag(&sVt[d*136 + mb]);
        accO[t] = __builtin_amdgcn_mfma_f32_16x16x32_bf16(af, bfv, accO[t], 0, 0, 0);
      }
    }
  }
  // epilogue: O / l
#pragma unroll
  for (int t = 0; t < 4; ++t) {
    const int d = t*16 + r;
#pragma unroll
    for (int rg = 0; rg < 4; ++rg) {
      const int row = n0 + wid*16 + qd*4 + rg;
      outb[((size_t)(b*N_ + row))*E_ + h*DH_ + d] = f2b(accO[t][rg] / lI[rg]);
    }
  }
}

// Merged prep: [0,1536) weight cvt; [1536,1536+4096) LN1; rest zero ebias.
#define SEG0 32768
#define SEG1 65536
#define SEG2 98304
#define SEG3 131072
#define SEG4 262144
#define SEG5 393216
#define PREP_LN0   1536
#define PREP_EB0   (1536 + 4096)
#define PREP_NB    (PREP_EB0 + 2048)
__global__ __launch_bounds__(256) void prep_k(
    const float* __restrict__ Wq, const float* __restrict__ Wk,
    const float* __restrict__ Wv, const float* __restrict__ Wo,
    const float* __restrict__ W1, const float* __restrict__ W2,
    u16* __restrict__ wq_b, u16* __restrict__ wk_b, u16* __restrict__ wv_b,
    u16* __restrict__ wo_b, u16* __restrict__ w1_b, u16* __restrict__ w2_b,
    const float* __restrict__ x, const float* __restrict__ g1,
    const float* __restrict__ bet1, u16* __restrict__ h_b,
    float* __restrict__ ebias) {
  if (blockIdx.x < PREP_LN0) {
    const int i = blockIdx.x*256 + threadIdx.x;
    const float* src; u16* dst; int base;
    if      (i < SEG0) { src = Wq; dst = wq_b; base = 0; }
    else if (i < SEG1) { src = Wk; dst = wk_b; base = SEG0; }
    else if (i < SEG2) { src = Wv; dst = wv_b; base = SEG1; }
    else if (i < SEG3) { src = Wo; dst = wo_b; base = SEG2; }
    else if (i < SEG4) { src = W1; dst = w1_b; base = SEG3; }
    else               { src = W2; dst = w2_b; base = SEG4; }
    const int li = i - base;
    const float4 f0 = *(const float4*)&src[(size_t)li*8];
    const float4 f1 = *(const float4*)&src[(size_t)li*8 + 4];
    u16x8 u;
    u[0]=f2b(f0.x); u[1]=f2b(f0.y); u[2]=f2b(f0.z); u[3]=f2b(f0.w);
    u[4]=f2b(f1.x); u[5]=f2b(f1.y); u[6]=f2b(f1.z); u[7]=f2b(f1.w);
    *(u16x8*)&dst[(size_t)li*8] = u;
  } else if (blockIdx.x < PREP_EB0) {
    const int row = blockIdx.x - PREP_LN0, t = threadIdx.x;
    const float v0 = x[(size_t)row*E_ + t], v1 = x[(size_t)row*E_ + t + 256];
    ln_store(v0, v1, g1, bet1, h_b, row, t);
  } else {
    const size_t i = ((size_t)(blockIdx.x - PREP_EB0)*256 + threadIdx.x)*4;
    *(float4*)&ebias[i] = float4{0.f, 0.f, 0.f, 0.f};
  }
}

extern "C" void kernel_launch(void* const* d_in, const int* in_sizes, int n_in,
                              void* d_out, int out_size, void* d_ws, size_t ws_size,
                              hipStream_t stream) {
  const float* x     = (const float*)d_in[0];
  const float* ea    = (const float*)d_in[1];
  const float* Wq    = (const float*)d_in[2];
  const float* bq    = (const float*)d_in[3];
  const float* Wk    = (const float*)d_in[4];
  const float* bk    = (const float*)d_in[5];
  const float* Wv    = (const float*)d_in[6];
  const float* bv    = (const float*)d_in[7];
  const float* Wo    = (const float*)d_in[8];
  const float* bo    = (const float*)d_in[9];
  const float* dtab  = (const float*)d_in[10];
  const float* We    = (const float*)d_in[11];
  const float* be    = (const float*)d_in[12];
  const float* W1    = (const float*)d_in[13];
  const float* b1    = (const float*)d_in[14];
  const float* W2    = (const float*)d_in[15];
  const float* b2    = (const float*)d_in[16];
  const float* g1    = (const float*)d_in[17];
  const float* bet1  = (const float*)d_in[18];
  const float* g2    = (const float*)d_in[19];
  const float* bet2  = (const float*)d_in[20];
  const int*   eidx  = (const int*)d_in[21];
  const int*   Dmat  = (const int*)d_in[22];
  float* out = (float*)d_out;

  char* ws = (char*)d_ws;
  size_t off = 0;
  auto alloc = [&](size_t bytes) -> void* {
    void* p = ws + off;
    off += (bytes + 255) & ~(size_t)255;
    return p;
  };
  u16* wq_b = (u16*)alloc((size_t)E_*E_*2);
  u16* wk_b = (u16*)alloc((size_t)E_*E_*2);
  u16* wv_b = (u16*)alloc((size_t)E_*E_*2);
  u16* wo_b = (u16*)alloc((size_t)E_*E_*2);
  u16* w1_b = (u16*)alloc((size_t)4*E_*E_*2);
  u16* w2_b = (u16*)alloc((size_t)4*E_*E_*2);
  u16* h_b  = (u16*)alloc((size_t)B_*N_*E_*2);
  u16* q_b  = (u16*)alloc((size_t)B_*N_*E_*2);
  u16* k_b  = (u16*)alloc((size_t)B_*N_*E_*2);
  u16* v_b  = (u16*)alloc((size_t)B_*N_*E_*2);
  float* ebias = (float*)alloc((size_t)H_*N_*N_*4);
  float* x1    = (float*)alloc((size_t)B_*N_*E_*4);
  u16*   h2_b  = (u16*)alloc((size_t)B_*N_*E_*2);
  u16*   mid_b = (u16*)alloc((size_t)B_*N_*4*E_*2);
  float* part  = (float*)alloc((size_t)4*B_*N_*E_*4);
  u16*   ao_b  = h_b;   // attn-out reuses h (dead after QKV)

  const int M = B_*N_;  // 4096

  // 1. weight conversions + LN1 + ebias zeroing (one launch)
  prep_k<<<dim3(PREP_NB), 256, 0, stream>>>(
      Wq, Wk, Wv, Wo, W1, W2, wq_b, wk_b, wv_b, wo_b, w1_b, w2_b,
      x, g1, bet1, h_b, ebias);

  // 2. QKV projections + edge encoder/scatter (one launch)
  qkv_edge_k<<<dim3(M/128, E_/128, 4), 256, 0, stream>>>(
      h_b, wq_b, wk_b, wv_b, bq, bk, bv, q_b, k_b, v_b,
      ea, We, be, eidx, ebias);

  // 3. fused flash attention
  flash_attn_k<<<dim3(N_/QT, B_*H_), 256, 0, stream>>>(
      q_b, k_b, v_b, dtab, Dmat, ebias, ao_b);

  // 4. Wo split-K=2, reduce fused with +bias +residual + LN2
  gemm_splitk_k<<<dim3(M/128, E_/128, 2), 256, 0, stream>>>(
      ao_b, wo_b, part, E_, E_, E_/2);
  splitk_reduce_ln_k<<<dim3(M), 256, 0, stream>>>(
      part, bo, x, x1, g2, bet2, h2_b);

  // 5. FFN1 with exact GELU
  gemm_epi<2><<<dim3(M/128, 4*E_/128), 256, 0, stream>>>(h2_b, w1_b, b1, nullptr, nullptr, mid_b, E_, 4*E_);

  // 6. FFN2 + residual -> out, split-K=4
  gemm_splitk_k<<<dim3(M/128, E_/128, 4), 256, 0, stream>>>(
      mid_b, w2_b, part, 4*E_, E_, E_);
  splitk_reduce_k<4><<<dim3(M*E_/1024), 256, 0, stream>>>(part, b2, x1, out);
}

// Round 9
// 276.796 us; speedup vs baseline: 1.0986x; 1.0986x over previous
//
#include <hip/hip_runtime.h>
#include <cstdint>
#include <cstddef>

#define B_  8
#define N_  512
#define E_  512
#define H_  8
#define DH_ 64
#define NE_ 16384
#define QT  64

using u16   = unsigned short;
using bf16x8 = __attribute__((ext_vector_type(8))) __bf16;
using u16x8  = __attribute__((ext_vector_type(8))) unsigned short;
using u16x4  = __attribute__((ext_vector_type(4))) unsigned short;
using f32x4  = __attribute__((ext_vector_type(4))) float;

// fp32 -> bf16 round-to-nearest-even
__device__ __forceinline__ u16 f2b(float f) {
  unsigned u = __builtin_bit_cast(unsigned, f);
  u += 0x7fffu + ((u >> 16) & 1u);
  return (u16)(u >> 16);
}

__device__ __forceinline__ bf16x8 ld_frag(const u16* p) {
  return __builtin_bit_cast(bf16x8, *(const u16x8*)p);
}

// Async global->LDS, 16B per lane. LDS dest is wave-uniform base + lane*16.
__device__ __forceinline__ void gld_lds16(const u16* g, u16* l) {
  __builtin_amdgcn_global_load_lds(
      (const __attribute__((address_space(1))) unsigned*)(g),
      (__attribute__((address_space(3))) unsigned*)(l), 16, 0, 0);
}

// ---------------------------------------------------------------------------
// Core 128x128 block-tile GEMM, C = A[128xK] * W[128xK]^T, bf16 in, fp32 acc.
// ---------------------------------------------------------------------------
__device__ __forceinline__ void gemm_core_128x128(
    const u16* __restrict__ At, int lda,
    const u16* __restrict__ Bt, int ldb, int K,
    u16* ldsA, u16* ldsB, f32x4 (&acc)[4][4]) {
  const int tid  = threadIdx.x;
  const int wid  = tid >> 6, lane = tid & 63;
  const int wr   = wid >> 1, wc = wid & 1;
  const int qd   = lane >> 4, r = lane & 15;
  const int mrow = tid >> 2, k0 = (tid & 3) * 8;
  const int wbase = wid << 9;          // u16 units: 64 lanes * 8 u16
  for (int kt = 0; kt < K; kt += 32) {
    __syncthreads();
    gld_lds16(&At[(size_t)mrow*lda + kt + k0],        ldsA + wbase);
    gld_lds16(&At[(size_t)(mrow+64)*lda + kt + k0],   ldsA + 64*32 + wbase);
    gld_lds16(&Bt[(size_t)mrow*ldb + kt + k0],        ldsB + wbase);
    gld_lds16(&Bt[(size_t)(mrow+64)*ldb + kt + k0],   ldsB + 64*32 + wbase);
    __syncthreads();
    bf16x8 af[4], bfv[4];
#pragma unroll
    for (int i = 0; i < 4; ++i) af[i] = ld_frag(&ldsA[(wr*64 + i*16 + r)*32 + qd*8]);
#pragma unroll
    for (int j = 0; j < 4; ++j) bfv[j] = ld_frag(&ldsB[(wc*64 + j*16 + r)*32 + qd*8]);
#pragma unroll
    for (int i = 0; i < 4; ++i)
#pragma unroll
      for (int j = 0; j < 4; ++j)
        acc[i][j] = __builtin_amdgcn_mfma_f32_16x16x32_bf16(af[i], bfv[j], acc[i][j], 0, 0, 0);
  }
}

// EPI 0: bf16 out = acc + bias
// EPI 1: f32  out = acc + bias + res
// EPI 2: bf16 out = gelu_exact(acc + bias)
template <int EPI>
__global__ __launch_bounds__(256) void gemm_epi(
    const u16* __restrict__ A, const u16* __restrict__ W,
    const float* __restrict__ bias, const float* __restrict__ res,
    float* __restrict__ outf, u16* __restrict__ outb, int Kd, int Nd) {
  __shared__ u16 ldsA[128*32];
  __shared__ u16 ldsB[128*32];
  const int bx = blockIdx.x, by = blockIdx.y;
  f32x4 acc[4][4] = {};
  gemm_core_128x128(A + (size_t)bx*128*Kd, Kd, W + (size_t)by*128*Kd, Kd, Kd,
                    ldsA, ldsB, acc);
  const int tid = threadIdx.x, wid = tid>>6, lane = tid&63;
  const int wr = wid>>1, wc = wid&1, qd = lane>>4, r = lane&15;
#pragma unroll
  for (int i = 0; i < 4; ++i) {
#pragma unroll
    for (int j = 0; j < 4; ++j) {
      const int grow = bx*128 + wr*64 + i*16 + qd*4;
      const int gcol = by*128 + wc*64 + j*16 + r;
      const float bb = bias[gcol];
#pragma unroll
      for (int rg = 0; rg < 4; ++rg) {
        float v = acc[i][j][rg] + bb;
        const size_t idx = (size_t)(grow + rg)*Nd + gcol;
        if constexpr (EPI == 0) {
          outb[idx] = f2b(v);
        } else if constexpr (EPI == 1) {
          outf[idx] = v + res[idx];
        } else {
          v = 0.5f * v * (1.0f + erff(v * 0.70710678118f));
          outb[idx] = f2b(v);
        }
      }
    }
  }
}

// Split-K GEMM: grid.z = K-slice; raw fp32 partials to part[s][M][Nd].
__global__ __launch_bounds__(256) void gemm_splitk_k(
    const u16* __restrict__ A, const u16* __restrict__ W,
    float* __restrict__ part, int Kd, int Nd, int Ks) {
  __shared__ u16 ldsA[128*32];
  __shared__ u16 ldsB[128*32];
  const int bx = blockIdx.x, by = blockIdx.y, s = blockIdx.z;
  f32x4 acc[4][4] = {};
  gemm_core_128x128(A + (size_t)bx*128*Kd + (size_t)s*Ks, Kd,
                    W + (size_t)by*128*Kd + (size_t)s*Ks, Kd, Ks,
                    ldsA, ldsB, acc);
  const int tid = threadIdx.x, wid = tid>>6, lane = tid&63;
  const int wr = wid>>1, wc = wid&1, qd = lane>>4, r = lane&15;
  float* po = part + (size_t)s*(B_*N_)*Nd;
#pragma unroll
  for (int i = 0; i < 4; ++i) {
#pragma unroll
    for (int j = 0; j < 4; ++j) {
      const int grow = bx*128 + wr*64 + i*16 + qd*4;
      const int gcol = by*128 + wc*64 + j*16 + r;
#pragma unroll
      for (int rg = 0; rg < 4; ++rg)
        po[(size_t)(grow + rg)*Nd + gcol] = acc[i][j][rg];
    }
  }
}

// out = sum_s part[s] + bias + res   (fp32, float4-vectorized; Nd == E_)
template <int S>
__global__ __launch_bounds__(256) void splitk_reduce_k(
    const float* __restrict__ part, const float* __restrict__ bias,
    const float* __restrict__ res, float* __restrict__ out) {
  const size_t base = ((size_t)blockIdx.x*256 + threadIdx.x) * 4;
  float4 v = *(const float4*)&res[base];
  const int col = (int)(base & (E_-1));
  const float4 bb = *(const float4*)&bias[col];
  v.x += bb.x; v.y += bb.y; v.z += bb.z; v.w += bb.w;
#pragma unroll
  for (int s = 0; s < S; ++s) {
    const float4 p = *(const float4*)&part[(size_t)s*(B_*N_*E_) + base];
    v.x += p.x; v.y += p.y; v.z += p.z; v.w += p.w;
  }
  *(float4*)&out[base] = v;
}

// LayerNorm helper: block of 256 threads, one row of 512.
__device__ __forceinline__ void ln_store(
    float v0, float v1, const float* __restrict__ g,
    const float* __restrict__ be, u16* __restrict__ outb, int row, int t) {
  float s = v0 + v1, ss = v0*v0 + v1*v1;
  for (int o = 32; o; o >>= 1) { s += __shfl_down(s, o); ss += __shfl_down(ss, o); }
  __shared__ float rs[4], rss[4];
  const int wid = t>>6, lane = t&63;
  if (!lane) { rs[wid] = s; rss[wid] = ss; }
  __syncthreads();
  s  = rs[0]+rs[1]+rs[2]+rs[3];
  ss = rss[0]+rss[1]+rss[2]+rss[3];
  const float mu   = s * (1.0f/E_);
  const float var  = ss * (1.0f/E_) - mu*mu;
  const float rstd = rsqrtf(var + 1e-5f);
  outb[(size_t)row*E_ + t]       = f2b((v0-mu)*rstd*g[t] + be[t]);
  outb[(size_t)row*E_ + t + 256] = f2b((v1-mu)*rstd*g[t+256] + be[t+256]);
}

// Wo split-K reduce (S=2) fused with +bias +residual -> x1 AND LN2 -> h2 bf16.
__global__ __launch_bounds__(256) void splitk_reduce_ln_k(
    const float* __restrict__ part, const float* __restrict__ bias,
    const float* __restrict__ res, float* __restrict__ x1,
    const float* __restrict__ g, const float* __restrict__ be,
    u16* __restrict__ h2b) {
  const int row = blockIdx.x, t = threadIdx.x;
  const size_t base = (size_t)row*E_;
  float v0 = res[base + t]       + bias[t];
  float v1 = res[base + t + 256] + bias[t + 256];
#pragma unroll
  for (int s = 0; s < 2; ++s) {
    v0 += part[(size_t)s*(B_*N_*E_) + base + t];
    v1 += part[(size_t)s*(B_*N_*E_) + base + t + 256];
  }
  x1[base + t] = v0; x1[base + t + 256] = v1;
  ln_store(v0, v1, g, be, h2b, row, t);
}

// Merged QKV projection: grid.z selects which of 3 GEMMs.
__global__ __launch_bounds__(256) void qkv_gemm_k(
    const u16* __restrict__ A,
    const u16* __restrict__ Wqb, const u16* __restrict__ Wkb, const u16* __restrict__ Wvb,
    const float* __restrict__ bq, const float* __restrict__ bk, const float* __restrict__ bv,
    u16* __restrict__ qo, u16* __restrict__ ko, u16* __restrict__ vo) {
  __shared__ u16 ldsA[128*32];
  __shared__ u16 ldsB[128*32];
  const int bx = blockIdx.x, by = blockIdx.y, z = blockIdx.z;
  const u16*   W    = z == 0 ? Wqb : (z == 1 ? Wkb : Wvb);
  const float* bias = z == 0 ? bq  : (z == 1 ? bk  : bv);
  u16*         outb = z == 0 ? qo  : (z == 1 ? ko  : vo);
  f32x4 acc[4][4] = {};
  gemm_core_128x128(A + (size_t)bx*128*E_, E_, W + (size_t)by*128*E_, E_, E_,
                    ldsA, ldsB, acc);
  const int tid = threadIdx.x, wid = tid>>6, lane = tid&63;
  const int wr = wid>>1, wc = wid&1, qd = lane>>4, r = lane&15;
#pragma unroll
  for (int i = 0; i < 4; ++i) {
#pragma unroll
    for (int j = 0; j < 4; ++j) {
      const int grow = bx*128 + wr*64 + i*16 + qd*4;
      const int gcol = by*128 + wc*64 + j*16 + r;
      const float bb = bias[gcol];
#pragma unroll
      for (int rg = 0; rg < 4; ++rg)
        outb[(size_t)(grow + rg)*E_ + gcol] = f2b(acc[i][j][rg] + bb);
    }
  }
}

// ---------------------------------------------------------------------------
// Flash attention, split-KV: R7-proven internals; grid.z = m-half (2 chunks
// each). Writes UNdivided fp32 O partial + per-row (m,l); combine kernel
// merges. No dynamic register indexing (scratch-spill lesson, R5/R6).
// ---------------------------------------------------------------------------
__global__ __launch_bounds__(256) void flash_attn_k(
    const u16* __restrict__ qm, const u16* __restrict__ km, const u16* __restrict__ vm,
    const float* __restrict__ dtab, const int* __restrict__ Dm,
    const float* __restrict__ ebias, float* __restrict__ Opart,
    float* __restrict__ Mb, float* __restrict__ Lb) {
  __shared__ u16 sK[2*128*32];    // [ks][row][32] 16 KB
  __shared__ u16 sP[64*136];      // [row][m] 17 KB (also Q staging temp)
  __shared__ u16 sVt[64*136];     // [d][m^swz] 17 KB
  __shared__ float sDt[104];
  __shared__ float sMax[2][QT], sSum[2][QT], sM[QT], sL[QT], sAlpha[QT];

  const int bx = blockIdx.x;
  const int bz = blockIdx.y; const int b = bz>>3, h = bz&7;
  const int mh = blockIdx.z;
  const int n0 = bx*QT;
  const int tid = threadIdx.x, wid = tid>>6, lane = tid&63;
  const int wr = wid>>1, wc = wid&1, qd = lane>>4, r = lane&15;
  const int lrow = lane>>2, lk = (lane&3)*8;

  const u16* Qg = qm + ((size_t)(b*N_ + n0))*E_ + h*DH_;
  const u16* Kg = km + (size_t)b*N_*E_ + h*DH_;
  const u16* Vg = vm + (size_t)b*N_*E_ + h*DH_;
  const int*   Db = Dm + (size_t)b*N_*N_;
  const float* Eb = ebias + (size_t)h*N_*N_;

  // Stage Q through sP temp, then lift fragments into registers.
#pragma unroll
  for (int ks = 0; ks < 2; ++ks)
    gld_lds16(&Qg[(size_t)(wid*16 + lrow)*E_ + ks*32 + lk], sP + ks*2048 + wid*512);
  for (int idx = tid; idx < 100; idx += 256) sDt[idx] = dtab[idx*H_ + h];
  if (tid < QT) { sM[tid] = -3.0e38f; sL[tid] = 0.f; }
  __syncthreads();
  bf16x8 qf[2][2];
#pragma unroll
  for (int ks = 0; ks < 2; ++ks)
#pragma unroll
    for (int i = 0; i < 2; ++i)
      qf[ks][i] = ld_frag(&sP[ks*2048 + (wr*32 + i*16 + r)*32 + qd*8]);

  f32x4 accO[2][2] = {};
  const int mbeg = mh*256;

  for (int mc = mbeg; mc < mbeg + 256; mc += 128) {
    __syncthreads();   // (1) protect LDS from prev-iter readers
#pragma unroll
    for (int t = 0; t < 2; ++t) {
      const int row0 = wid*32 + t*16;
#pragma unroll
      for (int ks = 0; ks < 2; ++ks)
        gld_lds16(&Kg[(size_t)(mc + row0 + lrow)*E_ + ks*32 + lk],
                  sK + ks*4096 + row0*32);
    }
#pragma unroll
    for (int it = 0; it < 4; ++it) {
      const int idx = it*256 + tid;
      const int m = idx>>3, d0 = (idx&7)*8;
      const int g = d0>>3;
      const u16x8 u = *(const u16x8*)&Vg[(size_t)(mc+m)*E_ + d0];
#pragma unroll
      for (int e = 0; e < 8; ++e)
        sVt[(d0+e)*136 + (m ^ (g<<3))] = u[e];   // static reg index; XOR swizzle
    }
    __syncthreads();   // (2) publish staged K/V
    // ---- S = Q K^T ----
    f32x4 accS[2][4] = {};
#pragma unroll
    for (int ks = 0; ks < 2; ++ks) {
      bf16x8 bfv[4];
#pragma unroll
      for (int j = 0; j < 4; ++j)
        bfv[j] = ld_frag(&sK[ks*4096 + (wc*64 + j*16 + r)*32 + qd*8]);
#pragma unroll
      for (int i = 0; i < 2; ++i)
#pragma unroll
        for (int j = 0; j < 4; ++j)
          accS[i][j] = __builtin_amdgcn_mfma_f32_16x16x32_bf16(qf[ks][i], bfv[j], accS[i][j], 0, 0, 0);
    }
    // ---- bias + per-row chunk max ----
    float rmax[2][4];
#pragma unroll
    for (int i = 0; i < 2; ++i)
#pragma unroll
      for (int rg = 0; rg < 4; ++rg) rmax[i][rg] = -3.0e38f;
#pragma unroll
    for (int i = 0; i < 2; ++i) {
      const int n = n0 + wr*32 + i*16 + qd*4;
#pragma unroll
      for (int j = 0; j < 4; ++j) {
        const int m = mc + wc*64 + j*16 + r;
#pragma unroll
        for (int rg = 0; rg < 4; ++rg) {
          int di = Db[(size_t)(n+rg)*N_ + m];
          di = di < 0 ? 0 : (di > 99 ? 99 : di);
          const float v = accS[i][j][rg]*0.125f + sDt[di] + Eb[(size_t)(n+rg)*N_ + m];
          accS[i][j][rg] = v;
          rmax[i][rg] = fmaxf(rmax[i][rg], v);
        }
      }
    }
#pragma unroll
    for (int i = 0; i < 2; ++i)
#pragma unroll
      for (int rg = 0; rg < 4; ++rg) {
        float v = rmax[i][rg];
        v = fmaxf(v, __shfl_xor(v, 1)); v = fmaxf(v, __shfl_xor(v, 2));
        v = fmaxf(v, __shfl_xor(v, 4)); v = fmaxf(v, __shfl_xor(v, 8));
        if (r == 0) sMax[wc][wr*32 + i*16 + qd*4 + rg] = v;
      }
    __syncthreads();   // (3) max exchange
    if (tid < QT) {
      const float mcx  = fmaxf(sMax[0][tid], sMax[1][tid]);
      const float mnew = fmaxf(sM[tid], mcx);
      sAlpha[tid] = __expf(sM[tid] - mnew);
      sM[tid] = mnew;
    }
    __syncthreads();   // (3b) m/alpha publish
    // ---- P = exp(S-m) -> sP (static j), row sums, O rescale ----
    float rsum[2][4];
#pragma unroll
    for (int i = 0; i < 2; ++i) {
      const int lr0 = wr*32 + i*16 + qd*4;
#pragma unroll
      for (int rg = 0; rg < 4; ++rg) {
        const float mrow = sM[lr0 + rg];
        float partial = 0.f;
#pragma unroll
        for (int j = 0; j < 4; ++j) {
          const float p = __expf(accS[i][j][rg] - mrow);
          partial += p;
          sP[(lr0+rg)*136 + wc*64 + j*16 + r] = f2b(p);
        }
        rsum[i][rg] = partial;
        const float a = sAlpha[lr0 + rg];
#pragma unroll
        for (int jj = 0; jj < 2; ++jj) accO[i][jj][rg] *= a;
      }
    }
#pragma unroll
    for (int i = 0; i < 2; ++i)
#pragma unroll
      for (int rg = 0; rg < 4; ++rg) {
        float v = rsum[i][rg];
        v += __shfl_xor(v, 1); v += __shfl_xor(v, 2);
        v += __shfl_xor(v, 4); v += __shfl_xor(v, 8);
        if (r == 0) sSum[wc][wr*32 + i*16 + qd*4 + rg] = v;
      }
    __syncthreads();   // (4) sum + sP publish
    if (tid < QT) sL[tid] = sL[tid]*sAlpha[tid] + sSum[0][tid] + sSum[1][tid];
    __syncthreads();   // (5) l publish
    // ---- O += P @ V ----
#pragma unroll
    for (int ks = 0; ks < 4; ++ks) {
      bf16x8 af[2], bfv[2];
#pragma unroll
      for (int i = 0; i < 2; ++i)
        af[i] = ld_frag(&sP[(wr*32 + i*16 + r)*136 + ks*32 + qd*8]);
#pragma unroll
      for (int jj = 0; jj < 2; ++jj) {
        const int d = wc*32 + jj*16 + r;
        const int mb = (ks*32 + qd*8) ^ (((d>>3)&7)<<3);
        bfv[jj] = ld_frag(&sVt[d*136 + mb]);
      }
#pragma unroll
      for (int i = 0; i < 2; ++i)
#pragma unroll
        for (int jj = 0; jj < 2; ++jj)
          accO[i][jj] = __builtin_amdgcn_mfma_f32_16x16x32_bf16(af[i], bfv[jj], accO[i][jj], 0, 0, 0);
    }
  }
  // epilogue: undivided fp32 partial + (m,l) per row
  float* op = Opart + (size_t)mh*(B_*N_*E_);
#pragma unroll
  for (int i = 0; i < 2; ++i) {
    const int lr0 = wr*32 + i*16 + qd*4;
#pragma unroll
    for (int jj = 0; jj < 2; ++jj) {
      const int d = wc*32 + jj*16 + r;
#pragma unroll
      for (int rg = 0; rg < 4; ++rg)
        op[((size_t)(b*N_ + n0 + lr0 + rg))*E_ + h*DH_ + d] = accO[i][jj][rg];
    }
  }
  if (tid < QT) {
    const size_t ml = ((size_t)mh*(B_*H_) + bz)*N_ + n0 + tid;
    Mb[ml] = sM[tid];
    Lb[ml] = sL[tid];
  }
}

// Combine the two KV-halves: O = (a0*O0 + a1*O1) / (a0*l0 + a1*l1), bf16 out.
__global__ __launch_bounds__(256) void splitkv_combine_k(
    const float* __restrict__ Opart, const float* __restrict__ Mb,
    const float* __restrict__ Lb, u16* __restrict__ outb) {
  const size_t base = ((size_t)blockIdx.x*256 + threadIdx.x) * 4;
  const int nrow = (int)(base >> 9);          // [0, 4096)
  const int col  = (int)(base & 511);
  const int b = nrow >> 9, n = nrow & 511;
  const int h = col >> 6;
  const size_t ml = ((size_t)(b*H_ + h))*N_ + n;
  const float m0 = Mb[ml], l0 = Lb[ml];
  const float m1 = Mb[(size_t)(B_*H_)*N_ + ml], l1 = Lb[(size_t)(B_*H_)*N_ + ml];
  const float M = fmaxf(m0, m1);
  const float a0 = __expf(m0 - M), a1 = __expf(m1 - M);
  const float inv = 1.0f / (a0*l0 + a1*l1);
  const float4 o0 = *(const float4*)&Opart[base];
  const float4 o1 = *(const float4*)&Opart[(size_t)(B_*N_*E_) + base];
  u16x4 o;
  o[0] = f2b((a0*o0.x + a1*o1.x)*inv);
  o[1] = f2b((a0*o0.y + a1*o1.y)*inv);
  o[2] = f2b((a0*o0.z + a1*o1.z)*inv);
  o[3] = f2b((a0*o0.w + a1*o1.w)*inv);
  *(u16x4*)&outb[base] = o;
}

// Merged prep: [0,1536) weight cvt; [1536,1536+4096) LN1; rest zero ebias.
#define SEG0 32768
#define SEG1 65536
#define SEG2 98304
#define SEG3 131072
#define SEG4 262144
#define SEG5 393216
#define PREP_LN0   1536
#define PREP_EB0   (1536 + 4096)
#define PREP_NB    (PREP_EB0 + 2048)
__global__ __launch_bounds__(256) void prep_k(
    const float* __restrict__ Wq, const float* __restrict__ Wk,
    const float* __restrict__ Wv, const float* __restrict__ Wo,
    const float* __restrict__ W1, const float* __restrict__ W2,
    u16* __restrict__ wq_b, u16* __restrict__ wk_b, u16* __restrict__ wv_b,
    u16* __restrict__ wo_b, u16* __restrict__ w1_b, u16* __restrict__ w2_b,
    const float* __restrict__ x, const float* __restrict__ g1,
    const float* __restrict__ bet1, u16* __restrict__ h_b,
    float* __restrict__ ebias) {
  if (blockIdx.x < PREP_LN0) {
    const int i = blockIdx.x*256 + threadIdx.x;
    const float* src; u16* dst; int base;
    if      (i < SEG0) { src = Wq; dst = wq_b; base = 0; }
    else if (i < SEG1) { src = Wk; dst = wk_b; base = SEG0; }
    else if (i < SEG2) { src = Wv; dst = wv_b; base = SEG1; }
    else if (i < SEG3) { src = Wo; dst = wo_b; base = SEG2; }
    else if (i < SEG4) { src = W1; dst = w1_b; base = SEG3; }
    else               { src = W2; dst = w2_b; base = SEG4; }
    const int li = i - base;
    const float4 f0 = *(const float4*)&src[(size_t)li*8];
    const float4 f1 = *(const float4*)&src[(size_t)li*8 + 4];
    u16x8 u;
    u[0]=f2b(f0.x); u[1]=f2b(f0.y); u[2]=f2b(f0.z); u[3]=f2b(f0.w);
    u[4]=f2b(f1.x); u[5]=f2b(f1.y); u[6]=f2b(f1.z); u[7]=f2b(f1.w);
    *(u16x8*)&dst[(size_t)li*8] = u;
  } else if (blockIdx.x < PREP_EB0) {
    const int row = blockIdx.x - PREP_LN0, t = threadIdx.x;
    const float v0 = x[(size_t)row*E_ + t], v1 = x[(size_t)row*E_ + t + 256];
    ln_store(v0, v1, g1, bet1, h_b, row, t);
  } else {
    const size_t i = ((size_t)(blockIdx.x - PREP_EB0)*256 + threadIdx.x)*4;
    *(float4*)&ebias[i] = float4{0.f, 0.f, 0.f, 0.f};
  }
}

// Fused edge encoder + scatter (R7-proven: 512 blocks, 8 edges/wave).
__global__ __launch_bounds__(256) void edge_enc_scatter_k(
    const float* __restrict__ ea, const float* __restrict__ We,
    const float* __restrict__ be, const int* __restrict__ ei,
    float* __restrict__ eb) {
  const int wglob = (blockIdx.x*256 + threadIdx.x) >> 6;
  const int lane  = threadIdx.x & 63;
  float w[8][8];
#pragma unroll
  for (int h = 0; h < 8; ++h) {
    const float4 f0 = *(const float4*)&We[h*E_ + lane*8];
    const float4 f1 = *(const float4*)&We[h*E_ + lane*8 + 4];
    w[h][0]=f0.x; w[h][1]=f0.y; w[h][2]=f0.z; w[h][3]=f0.w;
    w[h][4]=f1.x; w[h][5]=f1.y; w[h][6]=f1.z; w[h][7]=f1.w;
  }
  const float beh = (lane < 8) ? be[lane] : 0.f;
#pragma unroll 1
  for (int t = 0; t < NE_/2048; ++t) {
    const int e = wglob*(NE_/2048) + t;
    const float* ar = ea + (size_t)e*E_;
    const float4 a0 = *(const float4*)&ar[lane*8];
    const float4 a1 = *(const float4*)&ar[lane*8 + 4];
    const float a[8] = {a0.x,a0.y,a0.z,a0.w,a1.x,a1.y,a1.z,a1.w};
    float acc[8];
#pragma unroll
    for (int h = 0; h < 8; ++h) {
      float s = 0.f;
#pragma unroll
      for (int j = 0; j < 8; ++j) s += a[j]*w[h][j];
      acc[h] = s;
    }
#pragma unroll
    for (int h = 0; h < 8; ++h) {
      float v = acc[h];
      v += __shfl_xor(v, 1);  v += __shfl_xor(v, 2);  v += __shfl_xor(v, 4);
      v += __shfl_xor(v, 8);  v += __shfl_xor(v, 16); v += __shfl_xor(v, 32);
      acc[h] = v;
    }
    float myv = acc[0];
#pragma unroll
    for (int h = 1; h < 8; ++h) myv = (lane == h) ? acc[h] : myv;
    if (lane < 8) {
      const int s2 = ei[e], t2 = ei[NE_ + e];
      atomicAdd(&eb[((size_t)lane*N_ + s2)*N_ + t2], myv + beh);
    }
  }
}

extern "C" void kernel_launch(void* const* d_in, const int* in_sizes, int n_in,
                              void* d_out, int out_size, void* d_ws, size_t ws_size,
                              hipStream_t stream) {
  const float* x     = (const float*)d_in[0];
  const float* ea    = (const float*)d_in[1];
  const float* Wq    = (const float*)d_in[2];
  const float* bq    = (const float*)d_in[3];
  const float* Wk    = (const float*)d_in[4];
  const float* bk    = (const float*)d_in[5];
  const float* Wv    = (const float*)d_in[6];
  const float* bv    = (const float*)d_in[7];
  const float* Wo    = (const float*)d_in[8];
  const float* bo    = (const float*)d_in[9];
  const float* dtab  = (const float*)d_in[10];
  const float* We    = (const float*)d_in[11];
  const float* be    = (const float*)d_in[12];
  const float* W1    = (const float*)d_in[13];
  const float* b1    = (const float*)d_in[14];
  const float* W2    = (const float*)d_in[15];
  const float* b2    = (const float*)d_in[16];
  const float* g1    = (const float*)d_in[17];
  const float* bet1  = (const float*)d_in[18];
  const float* g2    = (const float*)d_in[19];
  const float* bet2  = (const float*)d_in[20];
  const int*   eidx  = (const int*)d_in[21];
  const int*   Dmat  = (const int*)d_in[22];
  float* out = (float*)d_out;

  char* ws = (char*)d_ws;
  size_t off = 0;
  auto alloc = [&](size_t bytes) -> void* {
    void* p = ws + off;
    off += (bytes + 255) & ~(size_t)255;
    return p;
  };
  u16* wq_b = (u16*)alloc((size_t)E_*E_*2);
  u16* wk_b = (u16*)alloc((size_t)E_*E_*2);
  u16* wv_b = (u16*)alloc((size_t)E_*E_*2);
  u16* wo_b = (u16*)alloc((size_t)E_*E_*2);
  u16* w1_b = (u16*)alloc((size_t)4*E_*E_*2);
  u16* w2_b = (u16*)alloc((size_t)4*E_*E_*2);
  u16* h_b  = (u16*)alloc((size_t)B_*N_*E_*2);
  u16* q_b  = (u16*)alloc((size_t)B_*N_*E_*2);
  u16* k_b  = (u16*)alloc((size_t)B_*N_*E_*2);
  u16* v_b  = (u16*)alloc((size_t)B_*N_*E_*2);
  float* ebias = (float*)alloc((size_t)H_*N_*N_*4);
  float* x1    = (float*)alloc((size_t)B_*N_*E_*4);
  u16*   h2_b  = (u16*)alloc((size_t)B_*N_*E_*2);
  u16*   mid_b = (u16*)alloc((size_t)B_*N_*4*E_*2);
  float* part  = (float*)alloc((size_t)4*B_*N_*E_*4);
  float* Mb    = (float*)alloc((size_t)2*B_*H_*N_*4);
  float* Lb    = (float*)alloc((size_t)2*B_*H_*N_*4);
  u16*   ao_b  = h_b;   // attn-out reuses h (dead after QKV)

  const int M = B_*N_;  // 4096

  // 1. weight conversions + LN1 + ebias zeroing (one launch)
  prep_k<<<dim3(PREP_NB), 256, 0, stream>>>(
      Wq, Wk, Wv, Wo, W1, W2, wq_b, wk_b, wv_b, wo_b, w1_b, w2_b,
      x, g1, bet1, h_b, ebias);

  // 2. QKV projections (single launch)
  qkv_gemm_k<<<dim3(M/128, E_/128, 3), 256, 0, stream>>>(
      h_b, wq_b, wk_b, wv_b, bq, bk, bv, q_b, k_b, v_b);

  // 3. edge encoder fused with scatter into ebias
  edge_enc_scatter_k<<<dim3(512), 256, 0, stream>>>(ea, We, be, eidx, ebias);

  // 4. flash attention, split-KV (grid.z = m-half); partials into `part`
  flash_attn_k<<<dim3(N_/QT, B_*H_, 2), 256, 0, stream>>>(
      q_b, k_b, v_b, dtab, Dmat, ebias, part, Mb, Lb);
  splitkv_combine_k<<<dim3(M*E_/1024), 256, 0, stream>>>(part, Mb, Lb, ao_b);

  // 5. Wo split-K=2, reduce fused with +bias +residual + LN2
  gemm_splitk_k<<<dim3(M/128, E_/128, 2), 256, 0, stream>>>(
      ao_b, wo_b, part, E_, E_, E_/2);
  splitk_reduce_ln_k<<<dim3(M), 256, 0, stream>>>(
      part, bo, x, x1, g2, bet2, h2_b);

  // 6. FFN1 with exact GELU
  gemm_epi<2><<<dim3(M/128, 4*E_/128), 256, 0, stream>>>(h2_b, w1_b, b1, nullptr, nullptr, mid_b, E_, 4*E_);

  // 7. FFN2 + residual -> out, split-K=4
  gemm_splitk_k<<<dim3(M/128, E_/128, 4), 256, 0, stream>>>(
      mid_b, w2_b, part, 4*E_, E_, E_);
  splitk_reduce_k<4><<<dim3(M*E_/1024), 256, 0, stream>>>(part, b2, x1, out);
}

// Round 10
// 262.369 us; speedup vs baseline: 1.1590x; 1.0550x over previous
//
#include <hip/hip_runtime.h>
#include <cstdint>
#include <cstddef>

#define B_  8
#define N_  512
#define E_  512
#define H_  8
#define DH_ 64
#define NE_ 16384
#define QT  64

using u16   = unsigned short;
using bf16x8 = __attribute__((ext_vector_type(8))) __bf16;
using u16x8  = __attribute__((ext_vector_type(8))) unsigned short;
using f32x4  = __attribute__((ext_vector_type(4))) float;

// fp32 -> bf16 round-to-nearest-even
__device__ __forceinline__ u16 f2b(float f) {
  unsigned u = __builtin_bit_cast(unsigned, f);
  u += 0x7fffu + ((u >> 16) & 1u);
  return (u16)(u >> 16);
}

__device__ __forceinline__ bf16x8 ld_frag(const u16* p) {
  return __builtin_bit_cast(bf16x8, *(const u16x8*)p);
}

// Async global->LDS, 16B per lane. LDS dest is wave-uniform base + lane*16.
__device__ __forceinline__ void gld_lds16(const u16* g, u16* l) {
  __builtin_amdgcn_global_load_lds(
      (const __attribute__((address_space(1))) unsigned*)(g),
      (__attribute__((address_space(3))) unsigned*)(l), 16, 0, 0);
}

// ---------------------------------------------------------------------------
// Core 128x128 block-tile GEMM, C = A[128xK] * W[128xK]^T, bf16 in, fp32 acc.
// ---------------------------------------------------------------------------
__device__ __forceinline__ void gemm_core_128x128(
    const u16* __restrict__ At, int lda,
    const u16* __restrict__ Bt, int ldb, int K,
    u16* ldsA, u16* ldsB, f32x4 (&acc)[4][4]) {
  const int tid  = threadIdx.x;
  const int wid  = tid >> 6, lane = tid & 63;
  const int wr   = wid >> 1, wc = wid & 1;
  const int qd   = lane >> 4, r = lane & 15;
  const int mrow = tid >> 2, k0 = (tid & 3) * 8;
  const int wbase = wid << 9;          // u16 units: 64 lanes * 8 u16
  for (int kt = 0; kt < K; kt += 32) {
    __syncthreads();
    gld_lds16(&At[(size_t)mrow*lda + kt + k0],        ldsA + wbase);
    gld_lds16(&At[(size_t)(mrow+64)*lda + kt + k0],   ldsA + 64*32 + wbase);
    gld_lds16(&Bt[(size_t)mrow*ldb + kt + k0],        ldsB + wbase);
    gld_lds16(&Bt[(size_t)(mrow+64)*ldb + kt + k0],   ldsB + 64*32 + wbase);
    __syncthreads();
    bf16x8 af[4], bfv[4];
#pragma unroll
    for (int i = 0; i < 4; ++i) af[i] = ld_frag(&ldsA[(wr*64 + i*16 + r)*32 + qd*8]);
#pragma unroll
    for (int j = 0; j < 4; ++j) bfv[j] = ld_frag(&ldsB[(wc*64 + j*16 + r)*32 + qd*8]);
#pragma unroll
    for (int i = 0; i < 4; ++i)
#pragma unroll
      for (int j = 0; j < 4; ++j)
        acc[i][j] = __builtin_amdgcn_mfma_f32_16x16x32_bf16(af[i], bfv[j], acc[i][j], 0, 0, 0);
  }
}

// EPI 0: bf16 out = acc + bias
// EPI 1: f32  out = acc + bias + res
// EPI 2: bf16 out = gelu_exact(acc + bias)
template <int EPI>
__global__ __launch_bounds__(256) void gemm_epi(
    const u16* __restrict__ A, const u16* __restrict__ W,
    const float* __restrict__ bias, const float* __restrict__ res,
    float* __restrict__ outf, u16* __restrict__ outb, int Kd, int Nd) {
  __shared__ u16 ldsA[128*32];
  __shared__ u16 ldsB[128*32];
  const int bx = blockIdx.x, by = blockIdx.y;
  f32x4 acc[4][4] = {};
  gemm_core_128x128(A + (size_t)bx*128*Kd, Kd, W + (size_t)by*128*Kd, Kd, Kd,
                    ldsA, ldsB, acc);
  const int tid = threadIdx.x, wid = tid>>6, lane = tid&63;
  const int wr = wid>>1, wc = wid&1, qd = lane>>4, r = lane&15;
#pragma unroll
  for (int i = 0; i < 4; ++i) {
#pragma unroll
    for (int j = 0; j < 4; ++j) {
      const int grow = bx*128 + wr*64 + i*16 + qd*4;
      const int gcol = by*128 + wc*64 + j*16 + r;
      const float bb = bias[gcol];
#pragma unroll
      for (int rg = 0; rg < 4; ++rg) {
        float v = acc[i][j][rg] + bb;
        const size_t idx = (size_t)(grow + rg)*Nd + gcol;
        if constexpr (EPI == 0) {
          outb[idx] = f2b(v);
        } else if constexpr (EPI == 1) {
          outf[idx] = v + res[idx];
        } else {
          v = 0.5f * v * (1.0f + erff(v * 0.70710678118f));
          outb[idx] = f2b(v);
        }
      }
    }
  }
}

// Split-K GEMM: grid.z = K-slice; raw fp32 partials to part[s][M][Nd].
__global__ __launch_bounds__(256) void gemm_splitk_k(
    const u16* __restrict__ A, const u16* __restrict__ W,
    float* __restrict__ part, int Kd, int Nd, int Ks) {
  __shared__ u16 ldsA[128*32];
  __shared__ u16 ldsB[128*32];
  const int bx = blockIdx.x, by = blockIdx.y, s = blockIdx.z;
  f32x4 acc[4][4] = {};
  gemm_core_128x128(A + (size_t)bx*128*Kd + (size_t)s*Ks, Kd,
                    W + (size_t)by*128*Kd + (size_t)s*Ks, Kd, Ks,
                    ldsA, ldsB, acc);
  const int tid = threadIdx.x, wid = tid>>6, lane = tid&63;
  const int wr = wid>>1, wc = wid&1, qd = lane>>4, r = lane&15;
  float* po = part + (size_t)s*(B_*N_)*Nd;
#pragma unroll
  for (int i = 0; i < 4; ++i) {
#pragma unroll
    for (int j = 0; j < 4; ++j) {
      const int grow = bx*128 + wr*64 + i*16 + qd*4;
      const int gcol = by*128 + wc*64 + j*16 + r;
#pragma unroll
      for (int rg = 0; rg < 4; ++rg)
        po[(size_t)(grow + rg)*Nd + gcol] = acc[i][j][rg];
    }
  }
}

// out = sum_s part[s] + bias + res   (fp32, float4-vectorized; Nd == E_)
template <int S>
__global__ __launch_bounds__(256) void splitk_reduce_k(
    const float* __restrict__ part, const float* __restrict__ bias,
    const float* __restrict__ res, float* __restrict__ out) {
  const size_t base = ((size_t)blockIdx.x*256 + threadIdx.x) * 4;
  float4 v = *(const float4*)&res[base];
  const int col = (int)(base & (E_-1));
  const float4 bb = *(const float4*)&bias[col];
  v.x += bb.x; v.y += bb.y; v.z += bb.z; v.w += bb.w;
#pragma unroll
  for (int s = 0; s < S; ++s) {
    const float4 p = *(const float4*)&part[(size_t)s*(B_*N_*E_) + base];
    v.x += p.x; v.y += p.y; v.z += p.z; v.w += p.w;
  }
  *(float4*)&out[base] = v;
}

// LayerNorm helper: block of 256 threads, one row of 512.
__device__ __forceinline__ void ln_store(
    float v0, float v1, const float* __restrict__ g,
    const float* __restrict__ be, u16* __restrict__ outb, int row, int t) {
  float s = v0 + v1, ss = v0*v0 + v1*v1;
  for (int o = 32; o; o >>= 1) { s += __shfl_down(s, o); ss += __shfl_down(ss, o); }
  __shared__ float rs[4], rss[4];
  const int wid = t>>6, lane = t&63;
  if (!lane) { rs[wid] = s; rss[wid] = ss; }
  __syncthreads();
  s  = rs[0]+rs[1]+rs[2]+rs[3];
  ss = rss[0]+rss[1]+rss[2]+rss[3];
  const float mu   = s * (1.0f/E_);
  const float var  = ss * (1.0f/E_) - mu*mu;
  const float rstd = rsqrtf(var + 1e-5f);
  outb[(size_t)row*E_ + t]       = f2b((v0-mu)*rstd*g[t] + be[t]);
  outb[(size_t)row*E_ + t + 256] = f2b((v1-mu)*rstd*g[t+256] + be[t+256]);
}

// Wo split-K reduce (S=2) fused with +bias +residual -> x1 AND LN2 -> h2 bf16.
__global__ __launch_bounds__(256) void splitk_reduce_ln_k(
    const float* __restrict__ part, const float* __restrict__ bias,
    const float* __restrict__ res, float* __restrict__ x1,
    const float* __restrict__ g, const float* __restrict__ be,
    u16* __restrict__ h2b) {
  const int row = blockIdx.x, t = threadIdx.x;
  const size_t base = (size_t)row*E_;
  float v0 = res[base + t]       + bias[t];
  float v1 = res[base + t + 256] + bias[t + 256];
#pragma unroll
  for (int s = 0; s < 2; ++s) {
    v0 += part[(size_t)s*(B_*N_*E_) + base + t];
    v1 += part[(size_t)s*(B_*N_*E_) + base + t + 256];
  }
  x1[base + t] = v0; x1[base + t + 256] = v1;
  ln_store(v0, v1, g, be, h2b, row, t);
}

// Merged QKV projection: grid.z selects which of 3 GEMMs.
__global__ __launch_bounds__(256) void qkv_gemm_k(
    const u16* __restrict__ A,
    const u16* __restrict__ Wqb, const u16* __restrict__ Wkb, const u16* __restrict__ Wvb,
    const float* __restrict__ bq, const float* __restrict__ bk, const float* __restrict__ bv,
    u16* __restrict__ qo, u16* __restrict__ ko, u16* __restrict__ vo) {
  __shared__ u16 ldsA[128*32];
  __shared__ u16 ldsB[128*32];
  const int bx = blockIdx.x, by = blockIdx.y, z = blockIdx.z;
  const u16*   W    = z == 0 ? Wqb : (z == 1 ? Wkb : Wvb);
  const float* bias = z == 0 ? bq  : (z == 1 ? bk  : bv);
  u16*         outb = z == 0 ? qo  : (z == 1 ? ko  : vo);
  f32x4 acc[4][4] = {};
  gemm_core_128x128(A + (size_t)bx*128*E_, E_, W + (size_t)by*128*E_, E_, E_,
                    ldsA, ldsB, acc);
  const int tid = threadIdx.x, wid = tid>>6, lane = tid&63;
  const int wr = wid>>1, wc = wid&1, qd = lane>>4, r = lane&15;
#pragma unroll
  for (int i = 0; i < 4; ++i) {
#pragma unroll
    for (int j = 0; j < 4; ++j) {
      const int grow = bx*128 + wr*64 + i*16 + qd*4;
      const int gcol = by*128 + wc*64 + j*16 + r;
      const float bb = bias[gcol];
#pragma unroll
      for (int rg = 0; rg < 4; ++rg)
        outb[(size_t)(grow + rg)*E_ + gcol] = f2b(acc[i][j][rg] + bb);
    }
  }
}

// ---------------------------------------------------------------------------
// Flash attention — R7-measured-best structure (best flash so far: ~35us).
// Register Q frags, per-head dist table, gld_lds16 K staging, XOR-swizzled
// sVt (conflict-free write, 16B-contiguous read), static register indexing
// only (R5/R6 scratch-spill lesson), bf16 output.
// ---------------------------------------------------------------------------
__global__ __launch_bounds__(256) void flash_attn_k(
    const u16* __restrict__ qm, const u16* __restrict__ km, const u16* __restrict__ vm,
    const float* __restrict__ dtab, const int* __restrict__ Dm,
    const float* __restrict__ ebias, u16* __restrict__ outb) {
  __shared__ u16 sK[2*128*32];    // [ks][row][32] 16 KB
  __shared__ u16 sP[64*136];      // [row][m] 17 KB (also Q staging temp)
  __shared__ u16 sVt[64*136];     // [d][m^swz] 17 KB
  __shared__ float sDt[104];
  __shared__ float sMax[2][QT], sSum[2][QT], sM[QT], sL[QT], sAlpha[QT];

  const int bx = blockIdx.x;
  const int bz = blockIdx.y; const int b = bz>>3, h = bz&7;
  const int n0 = bx*QT;
  const int tid = threadIdx.x, wid = tid>>6, lane = tid&63;
  const int wr = wid>>1, wc = wid&1, qd = lane>>4, r = lane&15;
  const int lrow = lane>>2, lk = (lane&3)*8;

  const u16* Qg = qm + ((size_t)(b*N_ + n0))*E_ + h*DH_;
  const u16* Kg = km + (size_t)b*N_*E_ + h*DH_;
  const u16* Vg = vm + (size_t)b*N_*E_ + h*DH_;
  const int*   Db = Dm + (size_t)b*N_*N_;
  const float* Eb = ebias + (size_t)h*N_*N_;

  // Stage Q through sP temp, then lift fragments into registers.
#pragma unroll
  for (int ks = 0; ks < 2; ++ks)
    gld_lds16(&Qg[(size_t)(wid*16 + lrow)*E_ + ks*32 + lk], sP + ks*2048 + wid*512);
  for (int idx = tid; idx < 100; idx += 256) sDt[idx] = dtab[idx*H_ + h];
  if (tid < QT) { sM[tid] = -3.0e38f; sL[tid] = 0.f; }
  __syncthreads();
  bf16x8 qf[2][2];
#pragma unroll
  for (int ks = 0; ks < 2; ++ks)
#pragma unroll
    for (int i = 0; i < 2; ++i)
      qf[ks][i] = ld_frag(&sP[ks*2048 + (wr*32 + i*16 + r)*32 + qd*8]);

  f32x4 accO[2][2] = {};

  for (int mc = 0; mc < N_; mc += 128) {
    __syncthreads();   // (1) protect LDS from prev-iter readers
#pragma unroll
    for (int t = 0; t < 2; ++t) {
      const int row0 = wid*32 + t*16;
#pragma unroll
      for (int ks = 0; ks < 2; ++ks)
        gld_lds16(&Kg[(size_t)(mc + row0 + lrow)*E_ + ks*32 + lk],
                  sK + ks*4096 + row0*32);
    }
#pragma unroll
    for (int it = 0; it < 4; ++it) {
      const int idx = it*256 + tid;
      const int m = idx>>3, d0 = (idx&7)*8;
      const int g = d0>>3;
      const u16x8 u = *(const u16x8*)&Vg[(size_t)(mc+m)*E_ + d0];
#pragma unroll
      for (int e = 0; e < 8; ++e)
        sVt[(d0+e)*136 + (m ^ (g<<3))] = u[e];   // static reg index; XOR swizzle
    }
    __syncthreads();   // (2) publish staged K/V
    // ---- S = Q K^T ----
    f32x4 accS[2][4] = {};
#pragma unroll
    for (int ks = 0; ks < 2; ++ks) {
      bf16x8 bfv[4];
#pragma unroll
      for (int j = 0; j < 4; ++j)
        bfv[j] = ld_frag(&sK[ks*4096 + (wc*64 + j*16 + r)*32 + qd*8]);
#pragma unroll
      for (int i = 0; i < 2; ++i)
#pragma unroll
        for (int j = 0; j < 4; ++j)
          accS[i][j] = __builtin_amdgcn_mfma_f32_16x16x32_bf16(qf[ks][i], bfv[j], accS[i][j], 0, 0, 0);
    }
    // ---- bias (inline Db/Eb loads) + per-row chunk max ----
    float rmax[2][4];
#pragma unroll
    for (int i = 0; i < 2; ++i)
#pragma unroll
      for (int rg = 0; rg < 4; ++rg) rmax[i][rg] = -3.0e38f;
#pragma unroll
    for (int i = 0; i < 2; ++i) {
      const int n = n0 + wr*32 + i*16 + qd*4;
#pragma unroll
      for (int j = 0; j < 4; ++j) {
        const int m = mc + wc*64 + j*16 + r;
#pragma unroll
        for (int rg = 0; rg < 4; ++rg) {
          int di = Db[(size_t)(n+rg)*N_ + m];
          di = di < 0 ? 0 : (di > 99 ? 99 : di);
          const float v = accS[i][j][rg]*0.125f + sDt[di] + Eb[(size_t)(n+rg)*N_ + m];
          accS[i][j][rg] = v;
          rmax[i][rg] = fmaxf(rmax[i][rg], v);
        }
      }
    }
#pragma unroll
    for (int i = 0; i < 2; ++i)
#pragma unroll
      for (int rg = 0; rg < 4; ++rg) {
        float v = rmax[i][rg];
        v = fmaxf(v, __shfl_xor(v, 1)); v = fmaxf(v, __shfl_xor(v, 2));
        v = fmaxf(v, __shfl_xor(v, 4)); v = fmaxf(v, __shfl_xor(v, 8));
        if (r == 0) sMax[wc][wr*32 + i*16 + qd*4 + rg] = v;
      }
    __syncthreads();   // (3) max exchange
    if (tid < QT) {
      const float mcx  = fmaxf(sMax[0][tid], sMax[1][tid]);
      const float mnew = fmaxf(sM[tid], mcx);
      sAlpha[tid] = __expf(sM[tid] - mnew);
      sM[tid] = mnew;
    }
    __syncthreads();   // (3b) m/alpha publish
    // ---- P = exp(S-m) -> sP (static j), row sums, O rescale ----
    float rsum[2][4];
#pragma unroll
    for (int i = 0; i < 2; ++i) {
      const int lr0 = wr*32 + i*16 + qd*4;
#pragma unroll
      for (int rg = 0; rg < 4; ++rg) {
        const float mrow = sM[lr0 + rg];
        float partial = 0.f;
#pragma unroll
        for (int j = 0; j < 4; ++j) {
          const float p = __expf(accS[i][j][rg] - mrow);
          partial += p;
          sP[(lr0+rg)*136 + wc*64 + j*16 + r] = f2b(p);
        }
        rsum[i][rg] = partial;
        const float a = sAlpha[lr0 + rg];
#pragma unroll
        for (int jj = 0; jj < 2; ++jj) accO[i][jj][rg] *= a;
      }
    }
#pragma unroll
    for (int i = 0; i < 2; ++i)
#pragma unroll
      for (int rg = 0; rg < 4; ++rg) {
        float v = rsum[i][rg];
        v += __shfl_xor(v, 1); v += __shfl_xor(v, 2);
        v += __shfl_xor(v, 4); v += __shfl_xor(v, 8);
        if (r == 0) sSum[wc][wr*32 + i*16 + qd*4 + rg] = v;
      }
    __syncthreads();   // (4) sum + sP publish
    if (tid < QT) sL[tid] = sL[tid]*sAlpha[tid] + sSum[0][tid] + sSum[1][tid];
    __syncthreads();   // (5) l publish
    // ---- O += P @ V ----
#pragma unroll
    for (int ks = 0; ks < 4; ++ks) {
      bf16x8 af[2], bfv[2];
#pragma unroll
      for (int i = 0; i < 2; ++i)
        af[i] = ld_frag(&sP[(wr*32 + i*16 + r)*136 + ks*32 + qd*8]);
#pragma unroll
      for (int jj = 0; jj < 2; ++jj) {
        const int d = wc*32 + jj*16 + r;
        const int mb = (ks*32 + qd*8) ^ (((d>>3)&7)<<3);
        bfv[jj] = ld_frag(&sVt[d*136 + mb]);
      }
#pragma unroll
      for (int i = 0; i < 2; ++i)
#pragma unroll
        for (int jj = 0; jj < 2; ++jj)
          accO[i][jj] = __builtin_amdgcn_mfma_f32_16x16x32_bf16(af[i], bfv[jj], accO[i][jj], 0, 0, 0);
    }
  }
  // epilogue: O / l
#pragma unroll
  for (int i = 0; i < 2; ++i) {
    const int lr0 = wr*32 + i*16 + qd*4;
#pragma unroll
    for (int jj = 0; jj < 2; ++jj) {
      const int d = wc*32 + jj*16 + r;
#pragma unroll
      for (int rg = 0; rg < 4; ++rg) {
        const float inv = 1.0f / sL[lr0 + rg];
        outb[((size_t)(b*N_ + n0 + lr0 + rg))*E_ + h*DH_ + d] = f2b(accO[i][jj][rg] * inv);
      }
    }
  }
}

// Merged prep: [0,1536) weight cvt; [1536,1536+4096) LN1; rest zero ebias.
#define SEG0 32768
#define SEG1 65536
#define SEG2 98304
#define SEG3 131072
#define SEG4 262144
#define SEG5 393216
#define PREP_LN0   1536
#define PREP_EB0   (1536 + 4096)
#define PREP_NB    (PREP_EB0 + 2048)
__global__ __launch_bounds__(256) void prep_k(
    const float* __restrict__ Wq, const float* __restrict__ Wk,
    const float* __restrict__ Wv, const float* __restrict__ Wo,
    const float* __restrict__ W1, const float* __restrict__ W2,
    u16* __restrict__ wq_b, u16* __restrict__ wk_b, u16* __restrict__ wv_b,
    u16* __restrict__ wo_b, u16* __restrict__ w1_b, u16* __restrict__ w2_b,
    const float* __restrict__ x, const float* __restrict__ g1,
    const float* __restrict__ bet1, u16* __restrict__ h_b,
    float* __restrict__ ebias) {
  if (blockIdx.x < PREP_LN0) {
    const int i = blockIdx.x*256 + threadIdx.x;
    const float* src; u16* dst; int base;
    if      (i < SEG0) { src = Wq; dst = wq_b; base = 0; }
    else if (i < SEG1) { src = Wk; dst = wk_b; base = SEG0; }
    else if (i < SEG2) { src = Wv; dst = wv_b; base = SEG1; }
    else if (i < SEG3) { src = Wo; dst = wo_b; base = SEG2; }
    else if (i < SEG4) { src = W1; dst = w1_b; base = SEG3; }
    else               { src = W2; dst = w2_b; base = SEG4; }
    const int li = i - base;
    const float4 f0 = *(const float4*)&src[(size_t)li*8];
    const float4 f1 = *(const float4*)&src[(size_t)li*8 + 4];
    u16x8 u;
    u[0]=f2b(f0.x); u[1]=f2b(f0.y); u[2]=f2b(f0.z); u[3]=f2b(f0.w);
    u[4]=f2b(f1.x); u[5]=f2b(f1.y); u[6]=f2b(f1.z); u[7]=f2b(f1.w);
    *(u16x8*)&dst[(size_t)li*8] = u;
  } else if (blockIdx.x < PREP_EB0) {
    const int row = blockIdx.x - PREP_LN0, t = threadIdx.x;
    const float v0 = x[(size_t)row*E_ + t], v1 = x[(size_t)row*E_ + t + 256];
    ln_store(v0, v1, g1, bet1, h_b, row, t);
  } else {
    const size_t i = ((size_t)(blockIdx.x - PREP_EB0)*256 + threadIdx.x)*4;
    *(float4*)&ebias[i] = float4{0.f, 0.f, 0.f, 0.f};
  }
}

// Fused edge encoder + scatter (proven: 512 blocks, 8 edges/wave).
__global__ __launch_bounds__(256) void edge_enc_scatter_k(
    const float* __restrict__ ea, const float* __restrict__ We,
    const float* __restrict__ be, const int* __restrict__ ei,
    float* __restrict__ eb) {
  const int wglob = (blockIdx.x*256 + threadIdx.x) >> 6;
  const int lane  = threadIdx.x & 63;
  float w[8][8];
#pragma unroll
  for (int h = 0; h < 8; ++h) {
    const float4 f0 = *(const float4*)&We[h*E_ + lane*8];
    const float4 f1 = *(const float4*)&We[h*E_ + lane*8 + 4];
    w[h][0]=f0.x; w[h][1]=f0.y; w[h][2]=f0.z; w[h][3]=f0.w;
    w[h][4]=f1.x; w[h][5]=f1.y; w[h][6]=f1.z; w[h][7]=f1.w;
  }
  const float beh = (lane < 8) ? be[lane] : 0.f;
#pragma unroll 1
  for (int t = 0; t < NE_/2048; ++t) {
    const int e = wglob*(NE_/2048) + t;
    const float* ar = ea + (size_t)e*E_;
    const float4 a0 = *(const float4*)&ar[lane*8];
    const float4 a1 = *(const float4*)&ar[lane*8 + 4];
    const float a[8] = {a0.x,a0.y,a0.z,a0.w,a1.x,a1.y,a1.z,a1.w};
    float acc[8];
#pragma unroll
    for (int h = 0; h < 8; ++h) {
      float s = 0.f;
#pragma unroll
      for (int j = 0; j < 8; ++j) s += a[j]*w[h][j];
      acc[h] = s;
    }
#pragma unroll
    for (int h = 0; h < 8; ++h) {
      float v = acc[h];
      v += __shfl_xor(v, 1);  v += __shfl_xor(v, 2);  v += __shfl_xor(v, 4);
      v += __shfl_xor(v, 8);  v += __shfl_xor(v, 16); v += __shfl_xor(v, 32);
      acc[h] = v;
    }
    float myv = acc[0];
#pragma unroll
    for (int h = 1; h < 8; ++h) myv = (lane == h) ? acc[h] : myv;
    if (lane < 8) {
      const int s2 = ei[e], t2 = ei[NE_ + e];
      atomicAdd(&eb[((size_t)lane*N_ + s2)*N_ + t2], myv + beh);
    }
  }
}

extern "C" void kernel_launch(void* const* d_in, const int* in_sizes, int n_in,
                              void* d_out, int out_size, void* d_ws, size_t ws_size,
                              hipStream_t stream) {
  const float* x     = (const float*)d_in[0];
  const float* ea    = (const float*)d_in[1];
  const float* Wq    = (const float*)d_in[2];
  const float* bq    = (const float*)d_in[3];
  const float* Wk    = (const float*)d_in[4];
  const float* bk    = (const float*)d_in[5];
  const float* Wv    = (const float*)d_in[6];
  const float* bv    = (const float*)d_in[7];
  const float* Wo    = (const float*)d_in[8];
  const float* bo    = (const float*)d_in[9];
  const float* dtab  = (const float*)d_in[10];
  const float* We    = (const float*)d_in[11];
  const float* be    = (const float*)d_in[12];
  const float* W1    = (const float*)d_in[13];
  const float* b1    = (const float*)d_in[14];
  const float* W2    = (const float*)d_in[15];
  const float* b2    = (const float*)d_in[16];
  const float* g1    = (const float*)d_in[17];
  const float* bet1  = (const float*)d_in[18];
  const float* g2    = (const float*)d_in[19];
  const float* bet2  = (const float*)d_in[20];
  const int*   eidx  = (const int*)d_in[21];
  const int*   Dmat  = (const int*)d_in[22];
  float* out = (float*)d_out;

  char* ws = (char*)d_ws;
  size_t off = 0;
  auto alloc = [&](size_t bytes) -> void* {
    void* p = ws + off;
    off += (bytes + 255) & ~(size_t)255;
    return p;
  };
  u16* wq_b = (u16*)alloc((size_t)E_*E_*2);
  u16* wk_b = (u16*)alloc((size_t)E_*E_*2);
  u16* wv_b = (u16*)alloc((size_t)E_*E_*2);
  u16* wo_b = (u16*)alloc((size_t)E_*E_*2);
  u16* w1_b = (u16*)alloc((size_t)4*E_*E_*2);
  u16* w2_b = (u16*)alloc((size_t)4*E_*E_*2);
  u16* h_b  = (u16*)alloc((size_t)B_*N_*E_*2);
  u16* q_b  = (u16*)alloc((size_t)B_*N_*E_*2);
  u16* k_b  = (u16*)alloc((size_t)B_*N_*E_*2);
  u16* v_b  = (u16*)alloc((size_t)B_*N_*E_*2);
  float* ebias = (float*)alloc((size_t)H_*N_*N_*4);
  float* x1    = (float*)alloc((size_t)B_*N_*E_*4);
  u16*   h2_b  = (u16*)alloc((size_t)B_*N_*E_*2);
  u16*   mid_b = (u16*)alloc((size_t)B_*N_*4*E_*2);
  float* part  = (float*)alloc((size_t)4*B_*N_*E_*4);
  u16*   ao_b  = h_b;   // attn-out reuses h (dead after QKV)

  const int M = B_*N_;  // 4096

  // 1. weight conversions + LN1 + ebias zeroing (one launch)
  prep_k<<<dim3(PREP_NB), 256, 0, stream>>>(
      Wq, Wk, Wv, Wo, W1, W2, wq_b, wk_b, wv_b, wo_b, w1_b, w2_b,
      x, g1, bet1, h_b, ebias);

  // 2. QKV projections (single launch)
  qkv_gemm_k<<<dim3(M/128, E_/128, 3), 256, 0, stream>>>(
      h_b, wq_b, wk_b, wv_b, bq, bk, bv, q_b, k_b, v_b);

  // 3. edge encoder fused with scatter into ebias
  edge_enc_scatter_k<<<dim3(512), 256, 0, stream>>>(ea, We, be, eidx, ebias);

  // 4. fused flash attention (R7-best structure)
  flash_attn_k<<<dim3(N_/QT, B_*H_), 256, 0, stream>>>(
      q_b, k_b, v_b, dtab, Dmat, ebias, ao_b);

  // 5. Wo split-K=2, reduce fused with +bias +residual + LN2
  gemm_splitk_k<<<dim3(M/128, E_/128, 2), 256, 0, stream>>>(
      ao_b, wo_b, part, E_, E_, E_/2);
  splitk_reduce_ln_k<<<dim3(M), 256, 0, stream>>>(
      part, bo, x, x1, g2, bet2, h2_b);

  // 6. FFN1 with exact GELU
  gemm_epi<2><<<dim3(M/128, 4*E_/128), 256, 0, stream>>>(h2_b, w1_b, b1, nullptr, nullptr, mid_b, E_, 4*E_);

  // 7. FFN2 + residual -> out, split-K=4
  gemm_splitk_k<<<dim3(M/128, E_/128, 4), 256, 0, stream>>>(
      mid_b, w2_b, part, 4*E_, E_, E_);
  splitk_reduce_k<4><<<dim3(M*E_/1024), 256, 0, stream>>>(part, b2, x1, out);
}

// Round 11
// 257.681 us; speedup vs baseline: 1.1801x; 1.0182x over previous
//
#include <hip/hip_runtime.h>
#include <cstdint>
#include <cstddef>

#define B_  8
#define N_  512
#define E_  512
#define H_  8
#define DH_ 64
#define NE_ 16384
#define QT  64

using u16   = unsigned short;
using bf16x8 = __attribute__((ext_vector_type(8))) __bf16;
using u16x8  = __attribute__((ext_vector_type(8))) unsigned short;
using f32x4  = __attribute__((ext_vector_type(4))) float;

// fp32 -> bf16 round-to-nearest-even
__device__ __forceinline__ u16 f2b(float f) {
  unsigned u = __builtin_bit_cast(unsigned, f);
  u += 0x7fffu + ((u >> 16) & 1u);
  return (u16)(u >> 16);
}

__device__ __forceinline__ bf16x8 ld_frag(const u16* p) {
  return __builtin_bit_cast(bf16x8, *(const u16x8*)p);
}

// Async global->LDS, 16B per lane. LDS dest is wave-uniform base + lane*16.
__device__ __forceinline__ void gld_lds16(const u16* g, u16* l) {
  __builtin_amdgcn_global_load_lds(
      (const __attribute__((address_space(1))) unsigned*)(g),
      (__attribute__((address_space(3))) unsigned*)(l), 16, 0, 0);
}

// ---------------------------------------------------------------------------
// Core 128x128 block-tile GEMM, C = A[128xK] * W[128xK]^T, bf16 in, fp32 acc.
// BK=64 via ks-split LDS [2][128][32] (same per-half bank geometry as the
// proven BK=32 tile): 32 MFMAs per barrier pair, half the barrier drains.
// LDS 32 KB/block -> 4 blocks/CU (m132's BK=128 at 64 KB regressed to 2).
// ---------------------------------------------------------------------------
__device__ __forceinline__ void gemm_core_128x128(
    const u16* __restrict__ At, int lda,
    const u16* __restrict__ Bt, int ldb, int K,
    u16* ldsA, u16* ldsB, f32x4 (&acc)[4][4]) {
  const int tid  = threadIdx.x;
  const int wid  = tid >> 6, lane = tid & 63;
  const int wr   = wid >> 1, wc = wid & 1;
  const int qd   = lane >> 4, r = lane & 15;
  const int mrow = tid >> 2, k0 = (tid & 3) * 8;
  const int wbase = wid << 9;          // u16 units: 64 lanes * 8 u16
  for (int kt = 0; kt < K; kt += 64) {
    __syncthreads();
#pragma unroll
    for (int ks = 0; ks < 2; ++ks) {
      gld_lds16(&At[(size_t)mrow*lda + kt + ks*32 + k0],      ldsA + ks*4096 + wbase);
      gld_lds16(&At[(size_t)(mrow+64)*lda + kt + ks*32 + k0], ldsA + ks*4096 + 2048 + wbase);
      gld_lds16(&Bt[(size_t)mrow*ldb + kt + ks*32 + k0],      ldsB + ks*4096 + wbase);
      gld_lds16(&Bt[(size_t)(mrow+64)*ldb + kt + ks*32 + k0], ldsB + ks*4096 + 2048 + wbase);
    }
    __syncthreads();
#pragma unroll
    for (int ks = 0; ks < 2; ++ks) {
      bf16x8 af[4], bfv[4];
#pragma unroll
      for (int i = 0; i < 4; ++i)
        af[i] = ld_frag(&ldsA[ks*4096 + (wr*64 + i*16 + r)*32 + qd*8]);
#pragma unroll
      for (int j = 0; j < 4; ++j)
        bfv[j] = ld_frag(&ldsB[ks*4096 + (wc*64 + j*16 + r)*32 + qd*8]);
#pragma unroll
      for (int i = 0; i < 4; ++i)
#pragma unroll
        for (int j = 0; j < 4; ++j)
          acc[i][j] = __builtin_amdgcn_mfma_f32_16x16x32_bf16(af[i], bfv[j], acc[i][j], 0, 0, 0);
    }
  }
}

// EPI 0: bf16 out = acc + bias
// EPI 1: f32  out = acc + bias + res
// EPI 2: bf16 out = gelu_exact(acc + bias)
template <int EPI>
__global__ __launch_bounds__(256) void gemm_epi(
    const u16* __restrict__ A, const u16* __restrict__ W,
    const float* __restrict__ bias, const float* __restrict__ res,
    float* __restrict__ outf, u16* __restrict__ outb, int Kd, int Nd) {
  __shared__ u16 ldsA[2*128*32];
  __shared__ u16 ldsB[2*128*32];
  const int bx = blockIdx.x, by = blockIdx.y;
  f32x4 acc[4][4] = {};
  gemm_core_128x128(A + (size_t)bx*128*Kd, Kd, W + (size_t)by*128*Kd, Kd, Kd,
                    ldsA, ldsB, acc);
  const int tid = threadIdx.x, wid = tid>>6, lane = tid&63;
  const int wr = wid>>1, wc = wid&1, qd = lane>>4, r = lane&15;
#pragma unroll
  for (int i = 0; i < 4; ++i) {
#pragma unroll
    for (int j = 0; j < 4; ++j) {
      const int grow = bx*128 + wr*64 + i*16 + qd*4;
      const int gcol = by*128 + wc*64 + j*16 + r;
      const float bb = bias[gcol];
#pragma unroll
      for (int rg = 0; rg < 4; ++rg) {
        float v = acc[i][j][rg] + bb;
        const size_t idx = (size_t)(grow + rg)*Nd + gcol;
        if constexpr (EPI == 0) {
          outb[idx] = f2b(v);
        } else if constexpr (EPI == 1) {
          outf[idx] = v + res[idx];
        } else {
          v = 0.5f * v * (1.0f + erff(v * 0.70710678118f));
          outb[idx] = f2b(v);
        }
      }
    }
  }
}

// Split-K GEMM: grid.z = K-slice; raw fp32 partials to part[s][M][Nd].
__global__ __launch_bounds__(256) void gemm_splitk_k(
    const u16* __restrict__ A, const u16* __restrict__ W,
    float* __restrict__ part, int Kd, int Nd, int Ks) {
  __shared__ u16 ldsA[2*128*32];
  __shared__ u16 ldsB[2*128*32];
  const int bx = blockIdx.x, by = blockIdx.y, s = blockIdx.z;
  f32x4 acc[4][4] = {};
  gemm_core_128x128(A + (size_t)bx*128*Kd + (size_t)s*Ks, Kd,
                    W + (size_t)by*128*Kd + (size_t)s*Ks, Kd, Ks,
                    ldsA, ldsB, acc);
  const int tid = threadIdx.x, wid = tid>>6, lane = tid&63;
  const int wr = wid>>1, wc = wid&1, qd = lane>>4, r = lane&15;
  float* po = part + (size_t)s*(B_*N_)*Nd;
#pragma unroll
  for (int i = 0; i < 4; ++i) {
#pragma unroll
    for (int j = 0; j < 4; ++j) {
      const int grow = bx*128 + wr*64 + i*16 + qd*4;
      const int gcol = by*128 + wc*64 + j*16 + r;
#pragma unroll
      for (int rg = 0; rg < 4; ++rg)
        po[(size_t)(grow + rg)*Nd + gcol] = acc[i][j][rg];
    }
  }
}

// out = sum_s part[s] + bias + res   (fp32, float4-vectorized; Nd == E_)
template <int S>
__global__ __launch_bounds__(256) void splitk_reduce_k(
    const float* __restrict__ part, const float* __restrict__ bias,
    const float* __restrict__ res, float* __restrict__ out) {
  const size_t base = ((size_t)blockIdx.x*256 + threadIdx.x) * 4;
  float4 v = *(const float4*)&res[base];
  const int col = (int)(base & (E_-1));
  const float4 bb = *(const float4*)&bias[col];
  v.x += bb.x; v.y += bb.y; v.z += bb.z; v.w += bb.w;
#pragma unroll
  for (int s = 0; s < S; ++s) {
    const float4 p = *(const float4*)&part[(size_t)s*(B_*N_*E_) + base];
    v.x += p.x; v.y += p.y; v.z += p.z; v.w += p.w;
  }
  *(float4*)&out[base] = v;
}

// LayerNorm helper: block of 256 threads, one row of 512.
__device__ __forceinline__ void ln_store(
    float v0, float v1, const float* __restrict__ g,
    const float* __restrict__ be, u16* __restrict__ outb, int row, int t) {
  float s = v0 + v1, ss = v0*v0 + v1*v1;
  for (int o = 32; o; o >>= 1) { s += __shfl_down(s, o); ss += __shfl_down(ss, o); }
  __shared__ float rs[4], rss[4];
  const int wid = t>>6, lane = t&63;
  if (!lane) { rs[wid] = s; rss[wid] = ss; }
  __syncthreads();
  s  = rs[0]+rs[1]+rs[2]+rs[3];
  ss = rss[0]+rss[1]+rss[2]+rss[3];
  const float mu   = s * (1.0f/E_);
  const float var  = ss * (1.0f/E_) - mu*mu;
  const float rstd = rsqrtf(var + 1e-5f);
  outb[(size_t)row*E_ + t]       = f2b((v0-mu)*rstd*g[t] + be[t]);
  outb[(size_t)row*E_ + t + 256] = f2b((v1-mu)*rstd*g[t+256] + be[t+256]);
}

// Wo split-K reduce (S=2) fused with +bias +residual -> x1 AND LN2 -> h2 bf16.
__global__ __launch_bounds__(256) void splitk_reduce_ln_k(
    const float* __restrict__ part, const float* __restrict__ bias,
    const float* __restrict__ res, float* __restrict__ x1,
    const float* __restrict__ g, const float* __restrict__ be,
    u16* __restrict__ h2b) {
  const int row = blockIdx.x, t = threadIdx.x;
  const size_t base = (size_t)row*E_;
  float v0 = res[base + t]       + bias[t];
  float v1 = res[base + t + 256] + bias[t + 256];
#pragma unroll
  for (int s = 0; s < 2; ++s) {
    v0 += part[(size_t)s*(B_*N_*E_) + base + t];
    v1 += part[(size_t)s*(B_*N_*E_) + base + t + 256];
  }
  x1[base + t] = v0; x1[base + t + 256] = v1;
  ln_store(v0, v1, g, be, h2b, row, t);
}

// Merged QKV projection: grid.z selects which of 3 GEMMs.
__global__ __launch_bounds__(256) void qkv_gemm_k(
    const u16* __restrict__ A,
    const u16* __restrict__ Wqb, const u16* __restrict__ Wkb, const u16* __restrict__ Wvb,
    const float* __restrict__ bq, const float* __restrict__ bk, const float* __restrict__ bv,
    u16* __restrict__ qo, u16* __restrict__ ko, u16* __restrict__ vo) {
  __shared__ u16 ldsA[2*128*32];
  __shared__ u16 ldsB[2*128*32];
  const int bx = blockIdx.x, by = blockIdx.y, z = blockIdx.z;
  const u16*   W    = z == 0 ? Wqb : (z == 1 ? Wkb : Wvb);
  const float* bias = z == 0 ? bq  : (z == 1 ? bk  : bv);
  u16*         outb = z == 0 ? qo  : (z == 1 ? ko  : vo);
  f32x4 acc[4][4] = {};
  gemm_core_128x128(A + (size_t)bx*128*E_, E_, W + (size_t)by*128*E_, E_, E_,
                    ldsA, ldsB, acc);
  const int tid = threadIdx.x, wid = tid>>6, lane = tid&63;
  const int wr = wid>>1, wc = wid&1, qd = lane>>4, r = lane&15;
#pragma unroll
  for (int i = 0; i < 4; ++i) {
#pragma unroll
    for (int j = 0; j < 4; ++j) {
      const int grow = bx*128 + wr*64 + i*16 + qd*4;
      const int gcol = by*128 + wc*64 + j*16 + r;
      const float bb = bias[gcol];
#pragma unroll
      for (int rg = 0; rg < 4; ++rg)
        outb[(size_t)(grow + rg)*E_ + gcol] = f2b(acc[i][j][rg] + bb);
    }
  }
}

// ---------------------------------------------------------------------------
// Flash attention — measured-best structure (R7/R10). Register Q frags,
// per-head dist table, gld_lds16 K staging, XOR-swizzled sVt, static
// register indexing only, bf16 output. UNCHANGED from R10.
// ---------------------------------------------------------------------------
__global__ __launch_bounds__(256) void flash_attn_k(
    const u16* __restrict__ qm, const u16* __restrict__ km, const u16* __restrict__ vm,
    const float* __restrict__ dtab, const int* __restrict__ Dm,
    const float* __restrict__ ebias, u16* __restrict__ outb) {
  __shared__ u16 sK[2*128*32];    // [ks][row][32] 16 KB
  __shared__ u16 sP[64*136];      // [row][m] 17 KB (also Q staging temp)
  __shared__ u16 sVt[64*136];     // [d][m^swz] 17 KB
  __shared__ float sDt[104];
  __shared__ float sMax[2][QT], sSum[2][QT], sM[QT], sL[QT], sAlpha[QT];

  const int bx = blockIdx.x;
  const int bz = blockIdx.y; const int b = bz>>3, h = bz&7;
  const int n0 = bx*QT;
  const int tid = threadIdx.x, wid = tid>>6, lane = tid&63;
  const int wr = wid>>1, wc = wid&1, qd = lane>>4, r = lane&15;
  const int lrow = lane>>2, lk = (lane&3)*8;

  const u16* Qg = qm + ((size_t)(b*N_ + n0))*E_ + h*DH_;
  const u16* Kg = km + (size_t)b*N_*E_ + h*DH_;
  const u16* Vg = vm + (size_t)b*N_*E_ + h*DH_;
  const int*   Db = Dm + (size_t)b*N_*N_;
  const float* Eb = ebias + (size_t)h*N_*N_;

  // Stage Q through sP temp, then lift fragments into registers.
#pragma unroll
  for (int ks = 0; ks < 2; ++ks)
    gld_lds16(&Qg[(size_t)(wid*16 + lrow)*E_ + ks*32 + lk], sP + ks*2048 + wid*512);
  for (int idx = tid; idx < 100; idx += 256) sDt[idx] = dtab[idx*H_ + h];
  if (tid < QT) { sM[tid] = -3.0e38f; sL[tid] = 0.f; }
  __syncthreads();
  bf16x8 qf[2][2];
#pragma unroll
  for (int ks = 0; ks < 2; ++ks)
#pragma unroll
    for (int i = 0; i < 2; ++i)
      qf[ks][i] = ld_frag(&sP[ks*2048 + (wr*32 + i*16 + r)*32 + qd*8]);

  f32x4 accO[2][2] = {};

  for (int mc = 0; mc < N_; mc += 128) {
    __syncthreads();   // (1) protect LDS from prev-iter readers
#pragma unroll
    for (int t = 0; t < 2; ++t) {
      const int row0 = wid*32 + t*16;
#pragma unroll
      for (int ks = 0; ks < 2; ++ks)
        gld_lds16(&Kg[(size_t)(mc + row0 + lrow)*E_ + ks*32 + lk],
                  sK + ks*4096 + row0*32);
    }
#pragma unroll
    for (int it = 0; it < 4; ++it) {
      const int idx = it*256 + tid;
      const int m = idx>>3, d0 = (idx&7)*8;
      const int g = d0>>3;
      const u16x8 u = *(const u16x8*)&Vg[(size_t)(mc+m)*E_ + d0];
#pragma unroll
      for (int e = 0; e < 8; ++e)
        sVt[(d0+e)*136 + (m ^ (g<<3))] = u[e];   // static reg index; XOR swizzle
    }
    __syncthreads();   // (2) publish staged K/V
    // ---- S = Q K^T ----
    f32x4 accS[2][4] = {};
#pragma unroll
    for (int ks = 0; ks < 2; ++ks) {
      bf16x8 bfv[4];
#pragma unroll
      for (int j = 0; j < 4; ++j)
        bfv[j] = ld_frag(&sK[ks*4096 + (wc*64 + j*16 + r)*32 + qd*8]);
#pragma unroll
      for (int i = 0; i < 2; ++i)
#pragma unroll
        for (int j = 0; j < 4; ++j)
          accS[i][j] = __builtin_amdgcn_mfma_f32_16x16x32_bf16(qf[ks][i], bfv[j], accS[i][j], 0, 0, 0);
    }
    // ---- bias (inline Db/Eb loads) + per-row chunk max ----
    float rmax[2][4];
#pragma unroll
    for (int i = 0; i < 2; ++i)
#pragma unroll
      for (int rg = 0; rg < 4; ++rg) rmax[i][rg] = -3.0e38f;
#pragma unroll
    for (int i = 0; i < 2; ++i) {
      const int n = n0 + wr*32 + i*16 + qd*4;
#pragma unroll
      for (int j = 0; j < 4; ++j) {
        const int m = mc + wc*64 + j*16 + r;
#pragma unroll
        for (int rg = 0; rg < 4; ++rg) {
          int di = Db[(size_t)(n+rg)*N_ + m];
          di = di < 0 ? 0 : (di > 99 ? 99 : di);
          const float v = accS[i][j][rg]*0.125f + sDt[di] + Eb[(size_t)(n+rg)*N_ + m];
          accS[i][j][rg] = v;
          rmax[i][rg] = fmaxf(rmax[i][rg], v);
        }
      }
    }
#pragma unroll
    for (int i = 0; i < 2; ++i)
#pragma unroll
      for (int rg = 0; rg < 4; ++rg) {
        float v = rmax[i][rg];
        v = fmaxf(v, __shfl_xor(v, 1)); v = fmaxf(v, __shfl_xor(v, 2));
        v = fmaxf(v, __shfl_xor(v, 4)); v = fmaxf(v, __shfl_xor(v, 8));
        if (r == 0) sMax[wc][wr*32 + i*16 + qd*4 + rg] = v;
      }
    __syncthreads();   // (3) max exchange
    if (tid < QT) {
      const float mcx  = fmaxf(sMax[0][tid], sMax[1][tid]);
      const float mnew = fmaxf(sM[tid], mcx);
      sAlpha[tid] = __expf(sM[tid] - mnew);
      sM[tid] = mnew;
    }
    __syncthreads();   // (3b) m/alpha publish
    // ---- P = exp(S-m) -> sP (static j), row sums, O rescale ----
    float rsum[2][4];
#pragma unroll
    for (int i = 0; i < 2; ++i) {
      const int lr0 = wr*32 + i*16 + qd*4;
#pragma unroll
      for (int rg = 0; rg < 4; ++rg) {
        const float mrow = sM[lr0 + rg];
        float partial = 0.f;
#pragma unroll
        for (int j = 0; j < 4; ++j) {
          const float p = __expf(accS[i][j][rg] - mrow);
          partial += p;
          sP[(lr0+rg)*136 + wc*64 + j*16 + r] = f2b(p);
        }
        rsum[i][rg] = partial;
        const float a = sAlpha[lr0 + rg];
#pragma unroll
        for (int jj = 0; jj < 2; ++jj) accO[i][jj][rg] *= a;
      }
    }
#pragma unroll
    for (int i = 0; i < 2; ++i)
#pragma unroll
      for (int rg = 0; rg < 4; ++rg) {
        float v = rsum[i][rg];
        v += __shfl_xor(v, 1); v += __shfl_xor(v, 2);
        v += __shfl_xor(v, 4); v += __shfl_xor(v, 8);
        if (r == 0) sSum[wc][wr*32 + i*16 + qd*4 + rg] = v;
      }
    __syncthreads();   // (4) sum + sP publish
    if (tid < QT) sL[tid] = sL[tid]*sAlpha[tid] + sSum[0][tid] + sSum[1][tid];
    __syncthreads();   // (5) l publish
    // ---- O += P @ V ----
#pragma unroll
    for (int ks = 0; ks < 4; ++ks) {
      bf16x8 af[2], bfv[2];
#pragma unroll
      for (int i = 0; i < 2; ++i)
        af[i] = ld_frag(&sP[(wr*32 + i*16 + r)*136 + ks*32 + qd*8]);
#pragma unroll
      for (int jj = 0; jj < 2; ++jj) {
        const int d = wc*32 + jj*16 + r;
        const int mb = (ks*32 + qd*8) ^ (((d>>3)&7)<<3);
        bfv[jj] = ld_frag(&sVt[d*136 + mb]);
      }
#pragma unroll
      for (int i = 0; i < 2; ++i)
#pragma unroll
        for (int jj = 0; jj < 2; ++jj)
          accO[i][jj] = __builtin_amdgcn_mfma_f32_16x16x32_bf16(af[i], bfv[jj], accO[i][jj], 0, 0, 0);
    }
  }
  // epilogue: O / l
#pragma unroll
  for (int i = 0; i < 2; ++i) {
    const int lr0 = wr*32 + i*16 + qd*4;
#pragma unroll
    for (int jj = 0; jj < 2; ++jj) {
      const int d = wc*32 + jj*16 + r;
#pragma unroll
      for (int rg = 0; rg < 4; ++rg) {
        const float inv = 1.0f / sL[lr0 + rg];
        outb[((size_t)(b*N_ + n0 + lr0 + rg))*E_ + h*DH_ + d] = f2b(accO[i][jj][rg] * inv);
      }
    }
  }
}

// Merged prep: [0,1536) weight cvt; [1536,1536+4096) LN1; rest zero ebias.
#define SEG0 32768
#define SEG1 65536
#define SEG2 98304
#define SEG3 131072
#define SEG4 262144
#define SEG5 393216
#define PREP_LN0   1536
#define PREP_EB0   (1536 + 4096)
#define PREP_NB    (PREP_EB0 + 2048)
__global__ __launch_bounds__(256) void prep_k(
    const float* __restrict__ Wq, const float* __restrict__ Wk,
    const float* __restrict__ Wv, const float* __restrict__ Wo,
    const float* __restrict__ W1, const float* __restrict__ W2,
    u16* __restrict__ wq_b, u16* __restrict__ wk_b, u16* __restrict__ wv_b,
    u16* __restrict__ wo_b, u16* __restrict__ w1_b, u16* __restrict__ w2_b,
    const float* __restrict__ x, const float* __restrict__ g1,
    const float* __restrict__ bet1, u16* __restrict__ h_b,
    float* __restrict__ ebias) {
  if (blockIdx.x < PREP_LN0) {
    const int i = blockIdx.x*256 + threadIdx.x;
    const float* src; u16* dst; int base;
    if      (i < SEG0) { src = Wq; dst = wq_b; base = 0; }
    else if (i < SEG1) { src = Wk; dst = wk_b; base = SEG0; }
    else if (i < SEG2) { src = Wv; dst = wv_b; base = SEG1; }
    else if (i < SEG3) { src = Wo; dst = wo_b; base = SEG2; }
    else if (i < SEG4) { src = W1; dst = w1_b; base = SEG3; }
    else               { src = W2; dst = w2_b; base = SEG4; }
    const int li = i - base;
    const float4 f0 = *(const float4*)&src[(size_t)li*8];
    const float4 f1 = *(const float4*)&src[(size_t)li*8 + 4];
    u16x8 u;
    u[0]=f2b(f0.x); u[1]=f2b(f0.y); u[2]=f2b(f0.z); u[3]=f2b(f0.w);
    u[4]=f2b(f1.x); u[5]=f2b(f1.y); u[6]=f2b(f1.z); u[7]=f2b(f1.w);
    *(u16x8*)&dst[(size_t)li*8] = u;
  } else if (blockIdx.x < PREP_EB0) {
    const int row = blockIdx.x - PREP_LN0, t = threadIdx.x;
    const float v0 = x[(size_t)row*E_ + t], v1 = x[(size_t)row*E_ + t + 256];
    ln_store(v0, v1, g1, bet1, h_b, row, t);
  } else {
    const size_t i = ((size_t)(blockIdx.x - PREP_EB0)*256 + threadIdx.x)*4;
    *(float4*)&ebias[i] = float4{0.f, 0.f, 0.f, 0.f};
  }
}

// Fused edge encoder + scatter (proven: 512 blocks, 8 edges/wave).
__global__ __launch_bounds__(256) void edge_enc_scatter_k(
    const float* __restrict__ ea, const float* __restrict__ We,
    const float* __restrict__ be, const int* __restrict__ ei,
    float* __restrict__ eb) {
  const int wglob = (blockIdx.x*256 + threadIdx.x) >> 6;
  const int lane  = threadIdx.x & 63;
  float w[8][8];
#pragma unroll
  for (int h = 0; h < 8; ++h) {
    const float4 f0 = *(const float4*)&We[h*E_ + lane*8];
    const float4 f1 = *(const float4*)&We[h*E_ + lane*8 + 4];
    w[h][0]=f0.x; w[h][1]=f0.y; w[h][2]=f0.z; w[h][3]=f0.w;
    w[h][4]=f1.x; w[h][5]=f1.y; w[h][6]=f1.z; w[h][7]=f1.w;
  }
  const float beh = (lane < 8) ? be[lane] : 0.f;
#pragma unroll 1
  for (int t = 0; t < NE_/2048; ++t) {
    const int e = wglob*(NE_/2048) + t;
    const float* ar = ea + (size_t)e*E_;
    const float4 a0 = *(const float4*)&ar[lane*8];
    const float4 a1 = *(const float4*)&ar[lane*8 + 4];
    const float a[8] = {a0.x,a0.y,a0.z,a0.w,a1.x,a1.y,a1.z,a1.w};
    float acc[8];
#pragma unroll
    for (int h = 0; h < 8; ++h) {
      float s = 0.f;
#pragma unroll
      for (int j = 0; j < 8; ++j) s += a[j]*w[h][j];
      acc[h] = s;
    }
#pragma unroll
    for (int h = 0; h < 8; ++h) {
      float v = acc[h];
      v += __shfl_xor(v, 1);  v += __shfl_xor(v, 2);  v += __shfl_xor(v, 4);
      v += __shfl_xor(v, 8);  v += __shfl_xor(v, 16); v += __shfl_xor(v, 32);
      acc[h] = v;
    }
    float myv = acc[0];
#pragma unroll
    for (int h = 1; h < 8; ++h) myv = (lane == h) ? acc[h] : myv;
    if (lane < 8) {
      const int s2 = ei[e], t2 = ei[NE_ + e];
      atomicAdd(&eb[((size_t)lane*N_ + s2)*N_ + t2], myv + beh);
    }
  }
}

extern "C" void kernel_launch(void* const* d_in, const int* in_sizes, int n_in,
                              void* d_out, int out_size, void* d_ws, size_t ws_size,
                              hipStream_t stream) {
  const float* x     = (const float*)d_in[0];
  const float* ea    = (const float*)d_in[1];
  const float* Wq    = (const float*)d_in[2];
  const float* bq    = (const float*)d_in[3];
  const float* Wk    = (const float*)d_in[4];
  const float* bk    = (const float*)d_in[5];
  const float* Wv    = (const float*)d_in[6];
  const float* bv    = (const float*)d_in[7];
  const float* Wo    = (const float*)d_in[8];
  const float* bo    = (const float*)d_in[9];
  const float* dtab  = (const float*)d_in[10];
  const float* We    = (const float*)d_in[11];
  const float* be    = (const float*)d_in[12];
  const float* W1    = (const float*)d_in[13];
  const float* b1    = (const float*)d_in[14];
  const float* W2    = (const float*)d_in[15];
  const float* b2    = (const float*)d_in[16];
  const float* g1    = (const float*)d_in[17];
  const float* bet1  = (const float*)d_in[18];
  const float* g2    = (const float*)d_in[19];
  const float* bet2  = (const float*)d_in[20];
  const int*   eidx  = (const int*)d_in[21];
  const int*   Dmat  = (const int*)d_in[22];
  float* out = (float*)d_out;

  char* ws = (char*)d_ws;
  size_t off = 0;
  auto alloc = [&](size_t bytes) -> void* {
    void* p = ws + off;
    off += (bytes + 255) & ~(size_t)255;
    return p;
  };
  u16* wq_b = (u16*)alloc((size_t)E_*E_*2);
  u16* wk_b = (u16*)alloc((size_t)E_*E_*2);
  u16* wv_b = (u16*)alloc((size_t)E_*E_*2);
  u16* wo_b = (u16*)alloc((size_t)E_*E_*2);
  u16* w1_b = (u16*)alloc((size_t)4*E_*E_*2);
  u16* w2_b = (u16*)alloc((size_t)4*E_*E_*2);
  u16* h_b  = (u16*)alloc((size_t)B_*N_*E_*2);
  u16* q_b  = (u16*)alloc((size_t)B_*N_*E_*2);
  u16* k_b  = (u16*)alloc((size_t)B_*N_*E_*2);
  u16* v_b  = (u16*)alloc((size_t)B_*N_*E_*2);
  float* ebias = (float*)alloc((size_t)H_*N_*N_*4);
  float* x1    = (float*)alloc((size_t)B_*N_*E_*4);
  u16*   h2_b  = (u16*)alloc((size_t)B_*N_*E_*2);
  u16*   mid_b = (u16*)alloc((size_t)B_*N_*4*E_*2);
  float* part  = (float*)alloc((size_t)4*B_*N_*E_*4);
  u16*   ao_b  = h_b;   // attn-out reuses h (dead after QKV)

  const int M = B_*N_;  // 4096

  // 1. weight conversions + LN1 + ebias zeroing (one launch)
  prep_k<<<dim3(PREP_NB), 256, 0, stream>>>(
      Wq, Wk, Wv, Wo, W1, W2, wq_b, wk_b, wv_b, wo_b, w1_b, w2_b,
      x, g1, bet1, h_b, ebias);

  // 2. QKV projections (single launch)
  qkv_gemm_k<<<dim3(M/128, E_/128, 3), 256, 0, stream>>>(
      h_b, wq_b, wk_b, wv_b, bq, bk, bv, q_b, k_b, v_b);

  // 3. edge encoder fused with scatter into ebias
  edge_enc_scatter_k<<<dim3(512), 256, 0, stream>>>(ea, We, be, eidx, ebias);

  // 4. fused flash attention (measured-best structure)
  flash_attn_k<<<dim3(N_/QT, B_*H_), 256, 0, stream>>>(
      q_b, k_b, v_b, dtab, Dmat, ebias, ao_b);

  // 5. Wo split-K=2, reduce fused with +bias +residual + LN2
  gemm_splitk_k<<<dim3(M/128, E_/128, 2), 256, 0, stream>>>(
      ao_b, wo_b, part, E_, E_, E_/2);
  splitk_reduce_ln_k<<<dim3(M), 256, 0, stream>>>(
      part, bo, x, x1, g2, bet2, h2_b);

  // 6. FFN1 with exact GELU
  gemm_epi<2><<<dim3(M/128, 4*E_/128), 256, 0, stream>>>(h2_b, w1_b, b1, nullptr, nullptr, mid_b, E_, 4*E_);

  // 7. FFN2 + residual -> out, split-K=4
  gemm_splitk_k<<<dim3(M/128, E_/128, 4), 256, 0, stream>>>(
      mid_b, w2_b, part, 4*E_, E_, E_);
  splitk_reduce_k<4><<<dim3(M*E_/1024), 256, 0, stream>>>(part, b2, x1, out);
}

// Round 12
// 252.631 us; speedup vs baseline: 1.2037x; 1.0200x over previous
//
#include <hip/hip_runtime.h>
#include <cstdint>
#include <cstddef>

#define B_  8
#define N_  512
#define E_  512
#define H_  8
#define DH_ 64
#define NE_ 16384
#define QT  64

using u16   = unsigned short;
using bf16x8 = __attribute__((ext_vector_type(8))) __bf16;
using u16x8  = __attribute__((ext_vector_type(8))) unsigned short;
using f32x4  = __attribute__((ext_vector_type(4))) float;

// fp32 -> bf16 round-to-nearest-even
__device__ __forceinline__ u16 f2b(float f) {
  unsigned u = __builtin_bit_cast(unsigned, f);
  u += 0x7fffu + ((u >> 16) & 1u);
  return (u16)(u >> 16);
}
// bf16 (as u16) -> fp32
__device__ __forceinline__ float b2f(u16 u) {
  return __builtin_bit_cast(float, (unsigned)u << 16);
}

__device__ __forceinline__ bf16x8 ld_frag(const u16* p) {
  return __builtin_bit_cast(bf16x8, *(const u16x8*)p);
}

// Async global->LDS, 16B per lane. LDS dest is wave-uniform base + lane*16.
__device__ __forceinline__ void gld_lds16(const u16* g, u16* l) {
  __builtin_amdgcn_global_load_lds(
      (const __attribute__((address_space(1))) unsigned*)(g),
      (__attribute__((address_space(3))) unsigned*)(l), 16, 0, 0);
}

// ---------------------------------------------------------------------------
// Core 128x128 block-tile GEMM, C = A[128xK] * W[128xK]^T, bf16 in, fp32 acc.
// BK=64 via ks-split LDS [2][128][32]: 32 MFMAs per barrier pair.
// ---------------------------------------------------------------------------
__device__ __forceinline__ void gemm_core_128x128(
    const u16* __restrict__ At, int lda,
    const u16* __restrict__ Bt, int ldb, int K,
    u16* ldsA, u16* ldsB, f32x4 (&acc)[4][4]) {
  const int tid  = threadIdx.x;
  const int wid  = tid >> 6, lane = tid & 63;
  const int wr   = wid >> 1, wc = wid & 1;
  const int qd   = lane >> 4, r = lane & 15;
  const int mrow = tid >> 2, k0 = (tid & 3) * 8;
  const int wbase = wid << 9;          // u16 units: 64 lanes * 8 u16
  for (int kt = 0; kt < K; kt += 64) {
    __syncthreads();
#pragma unroll
    for (int ks = 0; ks < 2; ++ks) {
      gld_lds16(&At[(size_t)mrow*lda + kt + ks*32 + k0],      ldsA + ks*4096 + wbase);
      gld_lds16(&At[(size_t)(mrow+64)*lda + kt + ks*32 + k0], ldsA + ks*4096 + 2048 + wbase);
      gld_lds16(&Bt[(size_t)mrow*ldb + kt + ks*32 + k0],      ldsB + ks*4096 + wbase);
      gld_lds16(&Bt[(size_t)(mrow+64)*ldb + kt + ks*32 + k0], ldsB + ks*4096 + 2048 + wbase);
    }
    __syncthreads();
#pragma unroll
    for (int ks = 0; ks < 2; ++ks) {
      bf16x8 af[4], bfv[4];
#pragma unroll
      for (int i = 0; i < 4; ++i)
        af[i] = ld_frag(&ldsA[ks*4096 + (wr*64 + i*16 + r)*32 + qd*8]);
#pragma unroll
      for (int j = 0; j < 4; ++j)
        bfv[j] = ld_frag(&ldsB[ks*4096 + (wc*64 + j*16 + r)*32 + qd*8]);
#pragma unroll
      for (int i = 0; i < 4; ++i)
#pragma unroll
        for (int j = 0; j < 4; ++j)
          acc[i][j] = __builtin_amdgcn_mfma_f32_16x16x32_bf16(af[i], bfv[j], acc[i][j], 0, 0, 0);
    }
  }
}

// EPI 0: bf16 out = acc + bias
// EPI 1: f32  out = acc + bias + res
// EPI 2: bf16 out = gelu_exact(acc + bias)
template <int EPI>
__global__ __launch_bounds__(256) void gemm_epi(
    const u16* __restrict__ A, const u16* __restrict__ W,
    const float* __restrict__ bias, const float* __restrict__ res,
    float* __restrict__ outf, u16* __restrict__ outb, int Kd, int Nd) {
  __shared__ u16 ldsA[2*128*32];
  __shared__ u16 ldsB[2*128*32];
  const int bx = blockIdx.x, by = blockIdx.y;
  f32x4 acc[4][4] = {};
  gemm_core_128x128(A + (size_t)bx*128*Kd, Kd, W + (size_t)by*128*Kd, Kd, Kd,
                    ldsA, ldsB, acc);
  const int tid = threadIdx.x, wid = tid>>6, lane = tid&63;
  const int wr = wid>>1, wc = wid&1, qd = lane>>4, r = lane&15;
#pragma unroll
  for (int i = 0; i < 4; ++i) {
#pragma unroll
    for (int j = 0; j < 4; ++j) {
      const int grow = bx*128 + wr*64 + i*16 + qd*4;
      const int gcol = by*128 + wc*64 + j*16 + r;
      const float bb = bias[gcol];
#pragma unroll
      for (int rg = 0; rg < 4; ++rg) {
        float v = acc[i][j][rg] + bb;
        const size_t idx = (size_t)(grow + rg)*Nd + gcol;
        if constexpr (EPI == 0) {
          outb[idx] = f2b(v);
        } else if constexpr (EPI == 1) {
          outf[idx] = v + res[idx];
        } else {
          v = 0.5f * v * (1.0f + erff(v * 0.70710678118f));
          outb[idx] = f2b(v);
        }
      }
    }
  }
}

// Split-K GEMM: grid.z = K-slice; bf16 partials to part[s][M][Nd]
// (halves split-K round-trip traffic; partial magnitudes ~0.1-0.5 so bf16
// costs ~1e-3 abs error vs 0.11 threshold).
__global__ __launch_bounds__(256) void gemm_splitk_k(
    const u16* __restrict__ A, const u16* __restrict__ W,
    u16* __restrict__ part, int Kd, int Nd, int Ks) {
  __shared__ u16 ldsA[2*128*32];
  __shared__ u16 ldsB[2*128*32];
  const int bx = blockIdx.x, by = blockIdx.y, s = blockIdx.z;
  f32x4 acc[4][4] = {};
  gemm_core_128x128(A + (size_t)bx*128*Kd + (size_t)s*Ks, Kd,
                    W + (size_t)by*128*Kd + (size_t)s*Ks, Kd, Ks,
                    ldsA, ldsB, acc);
  const int tid = threadIdx.x, wid = tid>>6, lane = tid&63;
  const int wr = wid>>1, wc = wid&1, qd = lane>>4, r = lane&15;
  u16* po = part + (size_t)s*(B_*N_)*Nd;
#pragma unroll
  for (int i = 0; i < 4; ++i) {
#pragma unroll
    for (int j = 0; j < 4; ++j) {
      const int grow = bx*128 + wr*64 + i*16 + qd*4;
      const int gcol = by*128 + wc*64 + j*16 + r;
#pragma unroll
      for (int rg = 0; rg < 4; ++rg)
        po[(size_t)(grow + rg)*Nd + gcol] = f2b(acc[i][j][rg]);
    }
  }
}

// out = sum_s part[s] + bias + res  (bf16 partials, 8 elems/thread; Nd==E_)
template <int S>
__global__ __launch_bounds__(256) void splitk_reduce_k(
    const u16* __restrict__ part, const float* __restrict__ bias,
    const float* __restrict__ res, float* __restrict__ out) {
  const size_t base = ((size_t)blockIdx.x*256 + threadIdx.x) * 8;
  const int col = (int)(base & (E_-1));
  const float4 r0 = *(const float4*)&res[base];
  const float4 r1 = *(const float4*)&res[base + 4];
  const float4 b0 = *(const float4*)&bias[col];
  const float4 b1 = *(const float4*)&bias[col + 4];
  float acc[8] = {r0.x+b0.x, r0.y+b0.y, r0.z+b0.z, r0.w+b0.w,
                  r1.x+b1.x, r1.y+b1.y, r1.z+b1.z, r1.w+b1.w};
#pragma unroll
  for (int s = 0; s < S; ++s) {
    const u16x8 p = *(const u16x8*)&part[(size_t)s*(B_*N_*E_) + base];
#pragma unroll
    for (int e = 0; e < 8; ++e) acc[e] += b2f(p[e]);
  }
  float4 o0{acc[0], acc[1], acc[2], acc[3]};
  float4 o1{acc[4], acc[5], acc[6], acc[7]};
  *(float4*)&out[base]     = o0;
  *(float4*)&out[base + 4] = o1;
}

// LayerNorm helper: block of 256 threads, one row of 512.
__device__ __forceinline__ void ln_store(
    float v0, float v1, const float* __restrict__ g,
    const float* __restrict__ be, u16* __restrict__ outb, int row, int t) {
  float s = v0 + v1, ss = v0*v0 + v1*v1;
  for (int o = 32; o; o >>= 1) { s += __shfl_down(s, o); ss += __shfl_down(ss, o); }
  __shared__ float rs[4], rss[4];
  const int wid = t>>6, lane = t&63;
  if (!lane) { rs[wid] = s; rss[wid] = ss; }
  __syncthreads();
  s  = rs[0]+rs[1]+rs[2]+rs[3];
  ss = rss[0]+rss[1]+rss[2]+rss[3];
  const float mu   = s * (1.0f/E_);
  const float var  = ss * (1.0f/E_) - mu*mu;
  const float rstd = rsqrtf(var + 1e-5f);
  outb[(size_t)row*E_ + t]       = f2b((v0-mu)*rstd*g[t] + be[t]);
  outb[(size_t)row*E_ + t + 256] = f2b((v1-mu)*rstd*g[t+256] + be[t+256]);
}

// Wo split-K reduce (S=4, bf16 partials) fused with +bias +residual -> x1
// AND LN2 -> h2 bf16.
__global__ __launch_bounds__(256) void splitk_reduce_ln_k(
    const u16* __restrict__ part, const float* __restrict__ bias,
    const float* __restrict__ res, float* __restrict__ x1,
    const float* __restrict__ g, const float* __restrict__ be,
    u16* __restrict__ h2b) {
  const int row = blockIdx.x, t = threadIdx.x;
  const size_t base = (size_t)row*E_;
  float v0 = res[base + t]       + bias[t];
  float v1 = res[base + t + 256] + bias[t + 256];
#pragma unroll
  for (int s = 0; s < 4; ++s) {
    v0 += b2f(part[(size_t)s*(B_*N_*E_) + base + t]);
    v1 += b2f(part[(size_t)s*(B_*N_*E_) + base + t + 256]);
  }
  x1[base + t] = v0; x1[base + t + 256] = v1;
  ln_store(v0, v1, g, be, h2b, row, t);
}

// Merged QKV projection: grid.z selects which of 3 GEMMs.
__global__ __launch_bounds__(256) void qkv_gemm_k(
    const u16* __restrict__ A,
    const u16* __restrict__ Wqb, const u16* __restrict__ Wkb, const u16* __restrict__ Wvb,
    const float* __restrict__ bq, const float* __restrict__ bk, const float* __restrict__ bv,
    u16* __restrict__ qo, u16* __restrict__ ko, u16* __restrict__ vo) {
  __shared__ u16 ldsA[2*128*32];
  __shared__ u16 ldsB[2*128*32];
  const int bx = blockIdx.x, by = blockIdx.y, z = blockIdx.z;
  const u16*   W    = z == 0 ? Wqb : (z == 1 ? Wkb : Wvb);
  const float* bias = z == 0 ? bq  : (z == 1 ? bk  : bv);
  u16*         outb = z == 0 ? qo  : (z == 1 ? ko  : vo);
  f32x4 acc[4][4] = {};
  gemm_core_128x128(A + (size_t)bx*128*E_, E_, W + (size_t)by*128*E_, E_, E_,
                    ldsA, ldsB, acc);
  const int tid = threadIdx.x, wid = tid>>6, lane = tid&63;
  const int wr = wid>>1, wc = wid&1, qd = lane>>4, r = lane&15;
#pragma unroll
  for (int i = 0; i < 4; ++i) {
#pragma unroll
    for (int j = 0; j < 4; ++j) {
      const int grow = bx*128 + wr*64 + i*16 + qd*4;
      const int gcol = by*128 + wc*64 + j*16 + r;
      const float bb = bias[gcol];
#pragma unroll
      for (int rg = 0; rg < 4; ++rg)
        outb[(size_t)(grow + rg)*E_ + gcol] = f2b(acc[i][j][rg] + bb);
    }
  }
}

// ---------------------------------------------------------------------------
// Flash attention — measured-best structure (R7/R10). UNCHANGED.
// ---------------------------------------------------------------------------
__global__ __launch_bounds__(256) void flash_attn_k(
    const u16* __restrict__ qm, const u16* __restrict__ km, const u16* __restrict__ vm,
    const float* __restrict__ dtab, const int* __restrict__ Dm,
    const float* __restrict__ ebias, u16* __restrict__ outb) {
  __shared__ u16 sK[2*128*32];    // [ks][row][32] 16 KB
  __shared__ u16 sP[64*136];      // [row][m] 17 KB (also Q staging temp)
  __shared__ u16 sVt[64*136];     // [d][m^swz] 17 KB
  __shared__ float sDt[104];
  __shared__ float sMax[2][QT], sSum[2][QT], sM[QT], sL[QT], sAlpha[QT];

  const int bx = blockIdx.x;
  const int bz = blockIdx.y; const int b = bz>>3, h = bz&7;
  const int n0 = bx*QT;
  const int tid = threadIdx.x, wid = tid>>6, lane = tid&63;
  const int wr = wid>>1, wc = wid&1, qd = lane>>4, r = lane&15;
  const int lrow = lane>>2, lk = (lane&3)*8;

  const u16* Qg = qm + ((size_t)(b*N_ + n0))*E_ + h*DH_;
  const u16* Kg = km + (size_t)b*N_*E_ + h*DH_;
  const u16* Vg = vm + (size_t)b*N_*E_ + h*DH_;
  const int*   Db = Dm + (size_t)b*N_*N_;
  const float* Eb = ebias + (size_t)h*N_*N_;

  // Stage Q through sP temp, then lift fragments into registers.
#pragma unroll
  for (int ks = 0; ks < 2; ++ks)
    gld_lds16(&Qg[(size_t)(wid*16 + lrow)*E_ + ks*32 + lk], sP + ks*2048 + wid*512);
  for (int idx = tid; idx < 100; idx += 256) sDt[idx] = dtab[idx*H_ + h];
  if (tid < QT) { sM[tid] = -3.0e38f; sL[tid] = 0.f; }
  __syncthreads();
  bf16x8 qf[2][2];
#pragma unroll
  for (int ks = 0; ks < 2; ++ks)
#pragma unroll
    for (int i = 0; i < 2; ++i)
      qf[ks][i] = ld_frag(&sP[ks*2048 + (wr*32 + i*16 + r)*32 + qd*8]);

  f32x4 accO[2][2] = {};

  for (int mc = 0; mc < N_; mc += 128) {
    __syncthreads();   // (1) protect LDS from prev-iter readers
#pragma unroll
    for (int t = 0; t < 2; ++t) {
      const int row0 = wid*32 + t*16;
#pragma unroll
      for (int ks = 0; ks < 2; ++ks)
        gld_lds16(&Kg[(size_t)(mc + row0 + lrow)*E_ + ks*32 + lk],
                  sK + ks*4096 + row0*32);
    }
#pragma unroll
    for (int it = 0; it < 4; ++it) {
      const int idx = it*256 + tid;
      const int m = idx>>3, d0 = (idx&7)*8;
      const int g = d0>>3;
      const u16x8 u = *(const u16x8*)&Vg[(size_t)(mc+m)*E_ + d0];
#pragma unroll
      for (int e = 0; e < 8; ++e)
        sVt[(d0+e)*136 + (m ^ (g<<3))] = u[e];   // static reg index; XOR swizzle
    }
    __syncthreads();   // (2) publish staged K/V
    // ---- S = Q K^T ----
    f32x4 accS[2][4] = {};
#pragma unroll
    for (int ks = 0; ks < 2; ++ks) {
      bf16x8 bfv[4];
#pragma unroll
      for (int j = 0; j < 4; ++j)
        bfv[j] = ld_frag(&sK[ks*4096 + (wc*64 + j*16 + r)*32 + qd*8]);
#pragma unroll
      for (int i = 0; i < 2; ++i)
#pragma unroll
        for (int j = 0; j < 4; ++j)
          accS[i][j] = __builtin_amdgcn_mfma_f32_16x16x32_bf16(qf[ks][i], bfv[j], accS[i][j], 0, 0, 0);
    }
    // ---- bias (inline Db/Eb loads) + per-row chunk max ----
    float rmax[2][4];
#pragma unroll
    for (int i = 0; i < 2; ++i)
#pragma unroll
      for (int rg = 0; rg < 4; ++rg) rmax[i][rg] = -3.0e38f;
#pragma unroll
    for (int i = 0; i < 2; ++i) {
      const int n = n0 + wr*32 + i*16 + qd*4;
#pragma unroll
      for (int j = 0; j < 4; ++j) {
        const int m = mc + wc*64 + j*16 + r;
#pragma unroll
        for (int rg = 0; rg < 4; ++rg) {
          int di = Db[(size_t)(n+rg)*N_ + m];
          di = di < 0 ? 0 : (di > 99 ? 99 : di);
          const float v = accS[i][j][rg]*0.125f + sDt[di] + Eb[(size_t)(n+rg)*N_ + m];
          accS[i][j][rg] = v;
          rmax[i][rg] = fmaxf(rmax[i][rg], v);
        }
      }
    }
#pragma unroll
    for (int i = 0; i < 2; ++i)
#pragma unroll
      for (int rg = 0; rg < 4; ++rg) {
        float v = rmax[i][rg];
        v = fmaxf(v, __shfl_xor(v, 1)); v = fmaxf(v, __shfl_xor(v, 2));
        v = fmaxf(v, __shfl_xor(v, 4)); v = fmaxf(v, __shfl_xor(v, 8));
        if (r == 0) sMax[wc][wr*32 + i*16 + qd*4 + rg] = v;
      }
    __syncthreads();   // (3) max exchange
    if (tid < QT) {
      const float mcx  = fmaxf(sMax[0][tid], sMax[1][tid]);
      const float mnew = fmaxf(sM[tid], mcx);
      sAlpha[tid] = __expf(sM[tid] - mnew);
      sM[tid] = mnew;
    }
    __syncthreads();   // (3b) m/alpha publish
    // ---- P = exp(S-m) -> sP (static j), row sums, O rescale ----
    float rsum[2][4];
#pragma unroll
    for (int i = 0; i < 2; ++i) {
      const int lr0 = wr*32 + i*16 + qd*4;
#pragma unroll
      for (int rg = 0; rg < 4; ++rg) {
        const float mrow = sM[lr0 + rg];
        float partial = 0.f;
#pragma unroll
        for (int j = 0; j < 4; ++j) {
          const float p = __expf(accS[i][j][rg] - mrow);
          partial += p;
          sP[(lr0+rg)*136 + wc*64 + j*16 + r] = f2b(p);
        }
        rsum[i][rg] = partial;
        const float a = sAlpha[lr0 + rg];
#pragma unroll
        for (int jj = 0; jj < 2; ++jj) accO[i][jj][rg] *= a;
      }
    }
#pragma unroll
    for (int i = 0; i < 2; ++i)
#pragma unroll
      for (int rg = 0; rg < 4; ++rg) {
        float v = rsum[i][rg];
        v += __shfl_xor(v, 1); v += __shfl_xor(v, 2);
        v += __shfl_xor(v, 4); v += __shfl_xor(v, 8);
        if (r == 0) sSum[wc][wr*32 + i*16 + qd*4 + rg] = v;
      }
    __syncthreads();   // (4) sum + sP publish
    if (tid < QT) sL[tid] = sL[tid]*sAlpha[tid] + sSum[0][tid] + sSum[1][tid];
    __syncthreads();   // (5) l publish
    // ---- O += P @ V ----
#pragma unroll
    for (int ks = 0; ks < 4; ++ks) {
      bf16x8 af[2], bfv[2];
#pragma unroll
      for (int i = 0; i < 2; ++i)
        af[i] = ld_frag(&sP[(wr*32 + i*16 + r)*136 + ks*32 + qd*8]);
#pragma unroll
      for (int jj = 0; jj < 2; ++jj) {
        const int d = wc*32 + jj*16 + r;
        const int mb = (ks*32 + qd*8) ^ (((d>>3)&7)<<3);
        bfv[jj] = ld_frag(&sVt[d*136 + mb]);
      }
#pragma unroll
      for (int i = 0; i < 2; ++i)
#pragma unroll
        for (int jj = 0; jj < 2; ++jj)
          accO[i][jj] = __builtin_amdgcn_mfma_f32_16x16x32_bf16(af[i], bfv[jj], accO[i][jj], 0, 0, 0);
    }
  }
  // epilogue: O / l
#pragma unroll
  for (int i = 0; i < 2; ++i) {
    const int lr0 = wr*32 + i*16 + qd*4;
#pragma unroll
    for (int jj = 0; jj < 2; ++jj) {
      const int d = wc*32 + jj*16 + r;
#pragma unroll
      for (int rg = 0; rg < 4; ++rg) {
        const float inv = 1.0f / sL[lr0 + rg];
        outb[((size_t)(b*N_ + n0 + lr0 + rg))*E_ + h*DH_ + d] = f2b(accO[i][jj][rg] * inv);
      }
    }
  }
}

// Merged prep: [0,1536) weight cvt; [1536,1536+4096) LN1; rest zero ebias.
#define SEG0 32768
#define SEG1 65536
#define SEG2 98304
#define SEG3 131072
#define SEG4 262144
#define SEG5 393216
#define PREP_LN0   1536
#define PREP_EB0   (1536 + 4096)
#define PREP_NB    (PREP_EB0 + 2048)
__global__ __launch_bounds__(256) void prep_k(
    const float* __restrict__ Wq, const float* __restrict__ Wk,
    const float* __restrict__ Wv, const float* __restrict__ Wo,
    const float* __restrict__ W1, const float* __restrict__ W2,
    u16* __restrict__ wq_b, u16* __restrict__ wk_b, u16* __restrict__ wv_b,
    u16* __restrict__ wo_b, u16* __restrict__ w1_b, u16* __restrict__ w2_b,
    const float* __restrict__ x, const float* __restrict__ g1,
    const float* __restrict__ bet1, u16* __restrict__ h_b,
    float* __restrict__ ebias) {
  if (blockIdx.x < PREP_LN0) {
    const int i = blockIdx.x*256 + threadIdx.x;
    const float* src; u16* dst; int base;
    if      (i < SEG0) { src = Wq; dst = wq_b; base = 0; }
    else if (i < SEG1) { src = Wk; dst = wk_b; base = SEG0; }
    else if (i < SEG2) { src = Wv; dst = wv_b; base = SEG1; }
    else if (i < SEG3) { src = Wo; dst = wo_b; base = SEG2; }
    else if (i < SEG4) { src = W1; dst = w1_b; base = SEG3; }
    else               { src = W2; dst = w2_b; base = SEG4; }
    const int li = i - base;
    const float4 f0 = *(const float4*)&src[(size_t)li*8];
    const float4 f1 = *(const float4*)&src[(size_t)li*8 + 4];
    u16x8 u;
    u[0]=f2b(f0.x); u[1]=f2b(f0.y); u[2]=f2b(f0.z); u[3]=f2b(f0.w);
    u[4]=f2b(f1.x); u[5]=f2b(f1.y); u[6]=f2b(f1.z); u[7]=f2b(f1.w);
    *(u16x8*)&dst[(size_t)li*8] = u;
  } else if (blockIdx.x < PREP_EB0) {
    const int row = blockIdx.x - PREP_LN0, t = threadIdx.x;
    const float v0 = x[(size_t)row*E_ + t], v1 = x[(size_t)row*E_ + t + 256];
    ln_store(v0, v1, g1, bet1, h_b, row, t);
  } else {
    const size_t i = ((size_t)(blockIdx.x - PREP_EB0)*256 + threadIdx.x)*4;
    *(float4*)&ebias[i] = float4{0.f, 0.f, 0.f, 0.f};
  }
}

// Fused edge encoder + scatter (proven: 512 blocks, 8 edges/wave).
__global__ __launch_bounds__(256) void edge_enc_scatter_k(
    const float* __restrict__ ea, const float* __restrict__ We,
    const float* __restrict__ be, const int* __restrict__ ei,
    float* __restrict__ eb) {
  const int wglob = (blockIdx.x*256 + threadIdx.x) >> 6;
  const int lane  = threadIdx.x & 63;
  float w[8][8];
#pragma unroll
  for (int h = 0; h < 8; ++h) {
    const float4 f0 = *(const float4*)&We[h*E_ + lane*8];
    const float4 f1 = *(const float4*)&We[h*E_ + lane*8 + 4];
    w[h][0]=f0.x; w[h][1]=f0.y; w[h][2]=f0.z; w[h][3]=f0.w;
    w[h][4]=f1.x; w[h][5]=f1.y; w[h][6]=f1.z; w[h][7]=f1.w;
  }
  const float beh = (lane < 8) ? be[lane] : 0.f;
#pragma unroll 1
  for (int t = 0; t < NE_/2048; ++t) {
    const int e = wglob*(NE_/2048) + t;
    const float* ar = ea + (size_t)e*E_;
    const float4 a0 = *(const float4*)&ar[lane*8];
    const float4 a1 = *(const float4*)&ar[lane*8 + 4];
    const float a[8] = {a0.x,a0.y,a0.z,a0.w,a1.x,a1.y,a1.z,a1.w};
    float acc[8];
#pragma unroll
    for (int h = 0; h < 8; ++h) {
      float s = 0.f;
#pragma unroll
      for (int j = 0; j < 8; ++j) s += a[j]*w[h][j];
      acc[h] = s;
    }
#pragma unroll
    for (int h = 0; h < 8; ++h) {
      float v = acc[h];
      v += __shfl_xor(v, 1);  v += __shfl_xor(v, 2);  v += __shfl_xor(v, 4);
      v += __shfl_xor(v, 8);  v += __shfl_xor(v, 16); v += __shfl_xor(v, 32);
      acc[h] = v;
    }
    float myv = acc[0];
#pragma unroll
    for (int h = 1; h < 8; ++h) myv = (lane == h) ? acc[h] : myv;
    if (lane < 8) {
      const int s2 = ei[e], t2 = ei[NE_ + e];
      atomicAdd(&eb[((size_t)lane*N_ + s2)*N_ + t2], myv + beh);
    }
  }
}

extern "C" void kernel_launch(void* const* d_in, const int* in_sizes, int n_in,
                              void* d_out, int out_size, void* d_ws, size_t ws_size,
                              hipStream_t stream) {
  const float* x     = (const float*)d_in[0];
  const float* ea    = (const float*)d_in[1];
  const float* Wq    = (const float*)d_in[2];
  const float* bq    = (const float*)d_in[3];
  const float* Wk    = (const float*)d_in[4];
  const float* bk    = (const float*)d_in[5];
  const float* Wv    = (const float*)d_in[6];
  const float* bv    = (const float*)d_in[7];
  const float* Wo    = (const float*)d_in[8];
  const float* bo    = (const float*)d_in[9];
  const float* dtab  = (const float*)d_in[10];
  const float* We    = (const float*)d_in[11];
  const float* be    = (const float*)d_in[12];
  const float* W1    = (const float*)d_in[13];
  const float* b1    = (const float*)d_in[14];
  const float* W2    = (const float*)d_in[15];
  const float* b2    = (const float*)d_in[16];
  const float* g1    = (const float*)d_in[17];
  const float* bet1  = (const float*)d_in[18];
  const float* g2    = (const float*)d_in[19];
  const float* bet2  = (const float*)d_in[20];
  const int*   eidx  = (const int*)d_in[21];
  const int*   Dmat  = (const int*)d_in[22];
  float* out = (float*)d_out;

  char* ws = (char*)d_ws;
  size_t off = 0;
  auto alloc = [&](size_t bytes) -> void* {
    void* p = ws + off;
    off += (bytes + 255) & ~(size_t)255;
    return p;
  };
  u16* wq_b = (u16*)alloc((size_t)E_*E_*2);
  u16* wk_b = (u16*)alloc((size_t)E_*E_*2);
  u16* wv_b = (u16*)alloc((size_t)E_*E_*2);
  u16* wo_b = (u16*)alloc((size_t)E_*E_*2);
  u16* w1_b = (u16*)alloc((size_t)4*E_*E_*2);
  u16* w2_b = (u16*)alloc((size_t)4*E_*E_*2);
  u16* h_b  = (u16*)alloc((size_t)B_*N_*E_*2);
  u16* q_b  = (u16*)alloc((size_t)B_*N_*E_*2);
  u16* k_b  = (u16*)alloc((size_t)B_*N_*E_*2);
  u16* v_b  = (u16*)alloc((size_t)B_*N_*E_*2);
  float* ebias = (float*)alloc((size_t)H_*N_*N_*4);
  float* x1    = (float*)alloc((size_t)B_*N_*E_*4);
  u16*   h2_b  = (u16*)alloc((size_t)B_*N_*E_*2);
  u16*   mid_b = (u16*)alloc((size_t)B_*N_*4*E_*2);
  u16*   part  = (u16*)alloc((size_t)4*B_*N_*E_*2);   // bf16 split-K partials
  u16*   ao_b  = h_b;   // attn-out reuses h (dead after QKV)

  const int M = B_*N_;  // 4096

  // 1. weight conversions + LN1 + ebias zeroing (one launch)
  prep_k<<<dim3(PREP_NB), 256, 0, stream>>>(
      Wq, Wk, Wv, Wo, W1, W2, wq_b, wk_b, wv_b, wo_b, w1_b, w2_b,
      x, g1, bet1, h_b, ebias);

  // 2. QKV projections (single launch)
  qkv_gemm_k<<<dim3(M/128, E_/128, 3), 256, 0, stream>>>(
      h_b, wq_b, wk_b, wv_b, bq, bk, bv, q_b, k_b, v_b);

  // 3. edge encoder fused with scatter into ebias
  edge_enc_scatter_k<<<dim3(512), 256, 0, stream>>>(ea, We, be, eidx, ebias);

  // 4. fused flash attention (measured-best structure)
  flash_attn_k<<<dim3(N_/QT, B_*H_), 256, 0, stream>>>(
      q_b, k_b, v_b, dtab, Dmat, ebias, ao_b);

  // 5. Wo split-K=4 (512 blocks = 2/CU), reduce fused +bias +residual +LN2
  gemm_splitk_k<<<dim3(M/128, E_/128, 4), 256, 0, stream>>>(
      ao_b, wo_b, part, E_, E_, E_/4);
  splitk_reduce_ln_k<<<dim3(M), 256, 0, stream>>>(
      part, bo, x, x1, g2, bet2, h2_b);

  // 6. FFN1 with exact GELU
  gemm_epi<2><<<dim3(M/128, 4*E_/128), 256, 0, stream>>>(h2_b, w1_b, b1, nullptr, nullptr, mid_b, E_, 4*E_);

  // 7. FFN2 + residual -> out, split-K=4 (bf16 partials)
  gemm_splitk_k<<<dim3(M/128, E_/128, 4), 256, 0, stream>>>(
      mid_b, w2_b, part, 4*E_, E_, E_);
  splitk_reduce_k<4><<<dim3(M*E_/2048), 256, 0, stream>>>(part, b2, x1, out);
}